// Round 1
// baseline (1608.990 us; speedup 1.0000x reference)
//
#include <hip/hip_runtime.h>
#include <hip/hip_bf16.h>
#include <math.h>

// Problem constants
#define BB 2
#define LL 4096
#define DD 2048
#define KK 32
#define KQ 4
#define MM 8
#define HH 8
#define MEM 256          // K*H
#define CTOT 288         // MEM+K
#define NQ 512           // KQ*H*M*2
#define FLAT 2048        // K*H*M
#define CMERG 4128       // K + 2*FLAT
#define NCHUNK 16
#define CHUNK 256        // L / NCHUNK
#define YDIM 768         // K*24
#define BL (BB*LL)       // 8192

// ---------------- generic fp32 tiled GEMM: C[M,N] = A[M,K] * B[K,N] ----------------
#define GBM 128
#define GBN 64
#define GBK 16

__global__ __launch_bounds__(256) void gemm_f32(const float* __restrict__ A,
                                                const float* __restrict__ Bm,
                                                float* __restrict__ C,
                                                int Md, int Nd, int Kd) {
    __shared__ float As[GBK][GBM];
    __shared__ float Bs[GBK][GBN];
    int tid = threadIdx.x;
    int tx = tid & 15;        // n dir
    int ty = tid >> 4;        // m dir
    int n0 = blockIdx.x * GBN;
    int m0 = blockIdx.y * GBM;

    float acc[8][4];
#pragma unroll
    for (int i = 0; i < 8; ++i)
#pragma unroll
        for (int j = 0; j < 4; ++j) acc[i][j] = 0.f;

    for (int k0 = 0; k0 < Kd; k0 += GBK) {
        // load A tile: 128x16 = 2048 elems, 8 per thread; consecutive tid -> consecutive k
#pragma unroll
        for (int e = 0; e < 8; ++e) {
            int idx = tid + e * 256;
            int mm = idx >> 4;
            int kk = idx & 15;
            As[kk][mm] = A[(size_t)(m0 + mm) * Kd + k0 + kk];
        }
        // load B tile: 16x64 = 1024 elems, 4 per thread; consecutive tid -> consecutive n
#pragma unroll
        for (int e = 0; e < 4; ++e) {
            int idx = tid + e * 256;
            int kk = idx >> 6;
            int nn = idx & 63;
            int col = n0 + nn;
            Bs[kk][nn] = (col < Nd) ? Bm[(size_t)(k0 + kk) * Nd + col] : 0.f;
        }
        __syncthreads();
#pragma unroll
        for (int kk = 0; kk < GBK; ++kk) {
            float4 b4 = *(const float4*)&Bs[kk][tx * 4];
            float4 a0 = *(const float4*)&As[kk][ty * 8];
            float4 a1 = *(const float4*)&As[kk][ty * 8 + 4];
            float av[8] = {a0.x, a0.y, a0.z, a0.w, a1.x, a1.y, a1.z, a1.w};
            float bv[4] = {b4.x, b4.y, b4.z, b4.w};
#pragma unroll
            for (int i = 0; i < 8; ++i)
#pragma unroll
                for (int j = 0; j < 4; ++j) acc[i][j] += av[i] * bv[j];
        }
        __syncthreads();
    }
#pragma unroll
    for (int i = 0; i < 8; ++i) {
        int row = m0 + ty * 8 + i;
#pragma unroll
        for (int j = 0; j < 4; ++j) {
            int col = n0 + tx * 4 + j;
            if (col < Nd) C[(size_t)row * Nd + col] = acc[i][j];
        }
    }
}

// ---------------- conv + scores + trig -> merged (b,l,4128) ----------------
__global__ __launch_bounds__(256) void convmerge(const float* __restrict__ z_pre,
                                                 const float* __restrict__ conv_k,
                                                 const float* __restrict__ theta,
                                                 const float* __restrict__ decay,
                                                 const float* __restrict__ anchor,
                                                 const float* __restrict__ sscale,
                                                 float* __restrict__ merged) {
    int bl = blockIdx.x;           // 0..8191
    int b = bl >> 12;
    int l = bl & 4095;
    int tid = threadIdx.x;
    __shared__ float zc[CTOT];
    __shared__ float pw[KK];

    for (int c = tid; c < CTOT; c += 256) {
        float acc = 0.f;
#pragma unroll
        for (int t = 0; t < 4; ++t) {
            int ls = l - 3 + t;
            float v = (ls >= 0) ? z_pre[(size_t)(b * LL + ls) * CTOT + c] : 0.f;
            acc += v * conv_k[t * CTOT + c];
        }
        zc[c] = acc;
    }
    __syncthreads();
    if (tid < KK) {
        int k = tid;
        float lw;
        if (k < KK - 4) {
            float xx = decay[k];
            float sp = (xx > 20.f) ? xx : log1pf(expf(xx));
            lw = -sp * (float)(LL - 1 - l);
        } else {
            float xx = anchor[k - (KK - 4)];
            float sp = (xx > 20.f) ? xx : log1pf(expf(xx));
            lw = -sp * (float)l;
        }
        float lp = sscale[k] * zc[MEM + k];
        lp = fminf(fmaxf(lp, -20.f), 20.f);
        float p = expf(lp + lw);
        pw[k] = p;
        merged[(size_t)bl * CMERG + k] = p;
    }
    __syncthreads();
    size_t base = (size_t)bl * CMERG;
    for (int idx = tid; idx < FLAT; idx += 256) {
        int k = idx >> 6;
        float kv = zc[idx >> 3];     // k*8+h
        float th = theta[idx];
        float phi = kv * th;
        float s, c;
        __sincosf(phi, &s, &c);
        float p = pw[k];
        merged[base + KK + idx] = p * c;
        merged[base + KK + FLAT + idx] = p * s;
    }
}

// ---------------- chunked cumsum over l, per (b, channel) ----------------
__global__ __launch_bounds__(256) void scan_pass1(const float* __restrict__ merged,
                                                  float* __restrict__ partials) {
    int c = blockIdx.x * 256 + threadIdx.x;
    int chunk = blockIdx.y;
    int b = blockIdx.z;
    if (c >= CMERG) return;
    size_t base = ((size_t)b * LL + (size_t)chunk * CHUNK) * CMERG + c;
    float s = 0.f;
    for (int i = 0; i < CHUNK; ++i) s += merged[base + (size_t)i * CMERG];
    partials[((size_t)b * NCHUNK + chunk) * CMERG + c] = s;
}

__global__ __launch_bounds__(256) void scan_pass2(float* __restrict__ partials) {
    int idx = blockIdx.x * 256 + threadIdx.x;
    if (idx >= BB * CMERG) return;
    int b = idx / CMERG;
    int c = idx % CMERG;
    float run = 0.f;
    for (int ch = 0; ch < NCHUNK; ++ch) {
        size_t p = ((size_t)b * NCHUNK + ch) * CMERG + c;
        float v = partials[p];
        partials[p] = run;      // exclusive
        run += v;
    }
}

__global__ __launch_bounds__(256) void scan_pass3(float* __restrict__ merged,
                                                  const float* __restrict__ partials) {
    int c = blockIdx.x * 256 + threadIdx.x;
    int chunk = blockIdx.y;
    int b = blockIdx.z;
    if (c >= CMERG) return;
    float run = partials[((size_t)b * NCHUNK + chunk) * CMERG + c];
    size_t base = ((size_t)b * LL + (size_t)chunk * CHUNK) * CMERG + c;
    for (int i = 0; i < CHUNK; ++i) {
        size_t p = base + (size_t)i * CMERG;
        run += merged[p];
        merged[p] = run;        // in-place inclusive cumsum
    }
}

// ---------------- state -> out_re/out_im -> per-k einsum -> swiglu -> y_act ----------------
__global__ __launch_bounds__(256) void stage_d(const float* __restrict__ cs,
                                               const float* __restrict__ q,
                                               const float* __restrict__ W_re,
                                               const float* __restrict__ W_im,
                                               const float* __restrict__ nscale,
                                               float* __restrict__ y_act) {
    int bl = blockIdx.x;
    int tid = threadIdx.x;
    __shared__ float csh[CMERG];
    __shared__ float qh[NQ];
    __shared__ float ore[256];
    __shared__ float oim[256];
    __shared__ float yh[KK * 48];

    size_t cbase = (size_t)bl * CMERG;
    for (int i = tid; i < CMERG; i += 256) csh[i] = cs[cbase + i];
    for (int i = tid; i < NQ; i += 256) qh[i] = q[(size_t)bl * NQ + i];
    __syncthreads();

    {
        int k = tid >> 3;
        int h = tid & 7;
        float den = fmaxf(csh[k], 1e-4f);
        float inv = 1.f / den;
        int kq = k >> 3;     // repeat factor 8
        float o_re = 0.f, o_im = 0.f;
#pragma unroll
        for (int m = 0; m < 8; ++m) {
            float sre = csh[KK + (tid << 3) + m] * inv;          // 32 + k*64+h*8+m
            float sim = csh[KK + FLAT + (tid << 3) + m] * inv;
            float qre = qh[((kq * 8 + h) * 8 + m) * 2 + 0];
            float qim = qh[((kq * 8 + h) * 8 + m) * 2 + 1];
            o_re += sre * qre + sim * qim;
            o_im += sim * qre - sre * qim;
        }
        float ns = nscale[tid];
        ore[tid] = o_re * ns;
        oim[tid] = o_im * ns;
    }
    __syncthreads();

    for (int idx = tid; idx < KK * 48; idx += 256) {
        int k = idx / 48;
        int n = idx % 48;
        float acc = 0.f;
#pragma unroll
        for (int h = 0; h < 8; ++h) {
            int kh = k * 8 + h;
            acc += ore[kh] * W_re[kh * 48 + n] + oim[kh] * W_im[kh * 48 + n];
        }
        yh[idx] = acc;
    }
    __syncthreads();

    for (int idx = tid; idx < YDIM; idx += 256) {
        int k = idx / 24;
        int n = idx % 24;
        float v = yh[k * 48 + n];
        float g = yh[k * 48 + 24 + n];
        float sg = g / (1.f + expf(-g));
        y_act[(size_t)bl * YDIM + idx] = v * sg;
    }
}

extern "C" void kernel_launch(void* const* d_in, const int* in_sizes, int n_in,
                              void* d_out, int out_size, void* d_ws, size_t ws_size,
                              hipStream_t stream) {
    const float* x      = (const float*)d_in[0];
    const float* W_mem  = (const float*)d_in[1];
    const float* conv_k = (const float*)d_in[2];
    const float* W_q    = (const float*)d_in[3];
    const float* theta  = (const float*)d_in[4];
    const float* decay  = (const float*)d_in[5];
    const float* anchor = (const float*)d_in[6];
    const float* sscale = (const float*)d_in[7];
    const float* W_re   = (const float*)d_in[8];
    const float* W_im   = (const float*)d_in[9];
    const float* nscale = (const float*)d_in[10];
    const float* W_out  = (const float*)d_in[11];
    float* out = (float*)d_out;
    float* ws = (float*)d_ws;

    const size_t n_z = (size_t)BL * CTOT;     // 2,359,296
    const size_t n_q = (size_t)BL * NQ;       // 4,194,304
    const size_t n_m = (size_t)BL * CMERG;    // 33,816,576
    const size_t n_p = (size_t)BB * NCHUNK * CMERG;  // 132,096
    const size_t n_y = (size_t)BL * YDIM;     // 6,291,456
    const size_t need = (n_z + n_q + n_m + n_p + n_y) * sizeof(float);

    float *z_pre, *qbuf, *merged, *partials, *y_act;
    if (ws_size >= need) {
        z_pre = ws;
        qbuf = z_pre + n_z;
        merged = qbuf + n_q;
        partials = merged + n_m;
        y_act = partials + n_p;
    } else {
        // stash z_pre and q inside d_out (dead before the final GEMM overwrites d_out)
        z_pre = out;
        qbuf = out + n_z;     // n_z+n_q = 6,553,600 < 16,777,216 elements of d_out
        merged = ws;
        partials = merged + n_m;
        y_act = partials + n_p;
    }

    // 1) z_pre = x @ W_mem   (8192 x 2048 x 288)
    gemm_f32<<<dim3((CTOT + GBN - 1) / GBN, BL / GBM), 256, 0, stream>>>(
        x, W_mem, z_pre, BL, CTOT, DD);
    // 2) q = x @ W_q         (8192 x 2048 x 512)
    gemm_f32<<<dim3(NQ / GBN, BL / GBM), 256, 0, stream>>>(
        x, W_q, qbuf, BL, NQ, DD);
    // 3) conv + p_w + trig -> merged
    convmerge<<<BL, 256, 0, stream>>>(z_pre, conv_k, theta, decay, anchor, sscale, merged);
    // 4-6) cumsum over l (chunked, in-place)
    scan_pass1<<<dim3((CMERG + 255) / 256, NCHUNK, BB), 256, 0, stream>>>(merged, partials);
    scan_pass2<<<dim3((BB * CMERG + 255) / 256), 256, 0, stream>>>(partials);
    scan_pass3<<<dim3((CMERG + 255) / 256, NCHUNK, BB), 256, 0, stream>>>(merged, partials);
    // 7) state/query contraction + einsum + swiglu -> y_act
    stage_d<<<BL, 256, 0, stream>>>(merged, qbuf, W_re, W_im, nscale, y_act);
    // 8) out = y_act @ W_out  (8192 x 768 x 2048)
    gemm_f32<<<dim3(DD / GBN, BL / GBM), 256, 0, stream>>>(y_act, W_out, out, BL, DD, YDIM);
}

// Round 2
// 310.689 us; speedup vs baseline: 5.1788x; 5.1788x over previous
//
#include <hip/hip_runtime.h>
#include <hip/hip_bf16.h>
#include <math.h>

// Problem constants
#define BB 2
#define LL 4096
#define DD 2048
#define KK 32
#define MEM 256          // K*H
#define CTOT 288         // MEM+K
#define NQ 512           // KQ*H*M*2
#define ZSTR 800         // CTOT + NQ (combined z|q GEMM output stride)
#define NPAD 896         // padded N for combined GEMM (7*128)
#define FLAT 2048        // K*H*M
#define CMERG 4128       // K + 2*FLAT
#define NCHUNK 16
#define CHUNK 256        // L / NCHUNK
#define YDIM 768         // K*24
#define BL (BB*LL)       // 8192

typedef __attribute__((ext_vector_type(4))) float f32x4;
typedef __attribute__((ext_vector_type(8))) short bf16x8;
typedef __attribute__((ext_vector_type(8))) unsigned short u16x8;
typedef unsigned short ushort_t;

__device__ inline unsigned short f2b(float v) {
    __hip_bfloat16 h = __float2bfloat16(v);
    return *reinterpret_cast<unsigned short*>(&h);
}
__device__ inline float b2f(unsigned short u) {
    __hip_bfloat16 h;
    *reinterpret_cast<unsigned short*>(&h) = u;
    return __bfloat162float(h);
}

__device__ inline void gload16(const void* g, void* l) {
    __builtin_amdgcn_global_load_lds(
        (const __attribute__((address_space(1))) unsigned int*)g,
        (__attribute__((address_space(3))) unsigned int*)l, 16, 0, 0);
}

// ---------------- converts / transposes ----------------
__global__ __launch_bounds__(256) void cvt_x(const float* __restrict__ x,
                                             unsigned short* __restrict__ xb) {
    size_t i = ((size_t)blockIdx.x * 256 + threadIdx.x) * 8;
    float4 a = *(const float4*)&x[i];
    float4 b = *(const float4*)&x[i + 4];
    u16x8 o;
    o[0] = f2b(a.x); o[1] = f2b(a.y); o[2] = f2b(a.z); o[3] = f2b(a.w);
    o[4] = f2b(b.x); o[5] = f2b(b.y); o[6] = f2b(b.z); o[7] = f2b(b.w);
    *(u16x8*)&xb[i] = o;
}

__global__ __launch_bounds__(256) void prep_wb(const float* __restrict__ W_mem,
                                               const float* __restrict__ W_q,
                                               unsigned short* __restrict__ Wb) {
    int n = blockIdx.x;   // 0..895
    for (int k = threadIdx.x; k < DD; k += 256) {
        float v = 0.f;
        if (n < CTOT) v = W_mem[(size_t)k * CTOT + n];
        else if (n < ZSTR) v = W_q[(size_t)k * NQ + (n - CTOT)];
        Wb[(size_t)n * DD + k] = f2b(v);
    }
}

__global__ __launch_bounds__(256) void prep_wo(const float* __restrict__ W_out,
                                               unsigned short* __restrict__ Whi,
                                               unsigned short* __restrict__ Wlo) {
    int n = blockIdx.x;   // 0..2047
    for (int k = threadIdx.x; k < YDIM; k += 256) {
        float v = W_out[(size_t)k * DD + n];
        unsigned short hi = f2b(v);
        float r = v - b2f(hi);
        Whi[(size_t)n * YDIM + k] = hi;
        Wlo[(size_t)n * YDIM + k] = f2b(r);
    }
}

// ---------------- bf16 MFMA GEMM: C[M,N] = A[M,K] * Bt[N,K]^T ----------------
// 128x128 tile, BK=32, 4 waves (each 64x64), global_load_lds staging,
// kseg XOR-swizzle (pre-swizzled source + swizzled read) to kill LDS conflicts.
template<bool SPLITB, bool CBF16>
__global__ __launch_bounds__(256) void gemm_mfma(const unsigned short* __restrict__ A,
                                                 const unsigned short* __restrict__ Bh_g,
                                                 const unsigned short* __restrict__ Bl_g,
                                                 void* __restrict__ Cout,
                                                 int Kd, int Nvalid, int Cstride) {
    __shared__ unsigned short As[4096];
    __shared__ unsigned short Bh[4096];
    __shared__ unsigned short Bl[SPLITB ? 4096 : 4];
    int tid = threadIdx.x;
    int lane = tid & 63;
    int wave = tid >> 6;
    int wr = wave >> 1, wc = wave & 1;
    int m0 = blockIdx.y * 128;
    int n0 = blockIdx.x * 128;

    f32x4 acc[4][4];
#pragma unroll
    for (int i = 0; i < 4; ++i)
#pragma unroll
        for (int j = 0; j < 4; ++j) acc[i][j] = (f32x4){0.f, 0.f, 0.f, 0.f};

    // staging: flat 16B-slot f = r*256 + tid; row = f>>2; slot kseg = f&3;
    // data kseg = (f&3) ^ ((row>>1)&3)  (XOR involution, same on read)
    int f0 = tid, f1 = 256 + tid;
    int row0 = f0 >> 2, ks0 = (f0 & 3) ^ ((row0 >> 1) & 3);
    int row1 = f1 >> 2, ks1 = (f1 & 3) ^ ((row1 >> 1) & 3);
    const unsigned short* ga0 = &A[(size_t)(m0 + row0) * Kd + ks0 * 8];
    const unsigned short* ga1 = &A[(size_t)(m0 + row1) * Kd + ks1 * 8];
    const unsigned short* gb0 = &Bh_g[(size_t)(n0 + row0) * Kd + ks0 * 8];
    const unsigned short* gb1 = &Bh_g[(size_t)(n0 + row1) * Kd + ks1 * 8];
    const unsigned short* gl0 = SPLITB ? &Bl_g[(size_t)(n0 + row0) * Kd + ks0 * 8] : nullptr;
    const unsigned short* gl1 = SPLITB ? &Bl_g[(size_t)(n0 + row1) * Kd + ks1 * 8] : nullptr;
    int l0 = (wave * 64) * 8;          // elem offset of this wave's round-0 chunk
    int l1 = (256 + wave * 64) * 8;    // round-1 chunk

    int g = lane >> 4, rr = lane & 15;

    for (int k0 = 0; k0 < Kd; k0 += 32) {
        if (k0) __syncthreads();
        gload16(ga0 + k0, &As[l0]);
        gload16(ga1 + k0, &As[l1]);
        gload16(gb0 + k0, &Bh[l0]);
        gload16(gb1 + k0, &Bh[l1]);
        if (SPLITB) {
            gload16(gl0 + k0, &Bl[l0]);
            gload16(gl1 + k0, &Bl[l1]);
        }
        __syncthreads();   // compiler drains vmcnt+lgkmcnt here

        bf16x8 av[4], bhv[4], blv[4];
#pragma unroll
        for (int i = 0; i < 4; ++i) {
            int ra = wr * 64 + i * 16 + rr;
            av[i] = *(const bf16x8*)&As[ra * 32 + ((g ^ ((ra >> 1) & 3)) * 8)];
            int rb = wc * 64 + i * 16 + rr;
            int ob = rb * 32 + ((g ^ ((rb >> 1) & 3)) * 8);
            bhv[i] = *(const bf16x8*)&Bh[ob];
            if (SPLITB) blv[i] = *(const bf16x8*)&Bl[ob];
        }
#pragma unroll
        for (int i = 0; i < 4; ++i)
#pragma unroll
            for (int j = 0; j < 4; ++j) {
                acc[i][j] = __builtin_amdgcn_mfma_f32_16x16x32_bf16(av[i], bhv[j], acc[i][j], 0, 0, 0);
                if (SPLITB)
                    acc[i][j] = __builtin_amdgcn_mfma_f32_16x16x32_bf16(av[i], blv[j], acc[i][j], 0, 0, 0);
            }
    }

    // epilogue: D lane mapping col=lane&15, row=(lane>>4)*4+reg
    int cg = lane >> 4, cr = lane & 15;
#pragma unroll
    for (int i = 0; i < 4; ++i)
#pragma unroll
        for (int j = 0; j < 4; ++j) {
            int colb = n0 + wc * 64 + j * 16 + cr;
            if (colb < Nvalid) {
#pragma unroll
                for (int r = 0; r < 4; ++r) {
                    int rowb = m0 + wr * 64 + i * 16 + cg * 4 + r;
                    if (CBF16)
                        ((unsigned short*)Cout)[(size_t)rowb * Cstride + colb] = f2b(acc[i][j][r]);
                    else
                        ((float*)Cout)[(size_t)rowb * Cstride + colb] = acc[i][j][r];
                }
            }
        }
}

// ---------------- conv + scores + trig -> merged (b,l,4128) ----------------
__global__ __launch_bounds__(256) void convmerge(const unsigned short* __restrict__ zq,
                                                 const float* __restrict__ conv_k,
                                                 const float* __restrict__ theta,
                                                 const float* __restrict__ decay,
                                                 const float* __restrict__ anchor,
                                                 const float* __restrict__ sscale,
                                                 float* __restrict__ merged) {
    int bl = blockIdx.x;           // 0..8191
    int b = bl >> 12;
    int l = bl & 4095;
    int tid = threadIdx.x;
    __shared__ float zc[CTOT];
    __shared__ float pw[KK];

    for (int c = tid; c < CTOT; c += 256) {
        float acc = 0.f;
#pragma unroll
        for (int t = 0; t < 4; ++t) {
            int ls = l - 3 + t;
            float v = (ls >= 0) ? b2f(zq[(size_t)(b * LL + ls) * ZSTR + c]) : 0.f;
            acc += v * conv_k[t * CTOT + c];
        }
        zc[c] = acc;
    }
    __syncthreads();
    if (tid < KK) {
        int k = tid;
        float lw;
        if (k < KK - 4) {
            float xx = decay[k];
            float sp = (xx > 20.f) ? xx : log1pf(expf(xx));
            lw = -sp * (float)(LL - 1 - l);
        } else {
            float xx = anchor[k - (KK - 4)];
            float sp = (xx > 20.f) ? xx : log1pf(expf(xx));
            lw = -sp * (float)l;
        }
        float lp = sscale[k] * zc[MEM + k];
        lp = fminf(fmaxf(lp, -20.f), 20.f);
        float p = expf(lp + lw);
        pw[k] = p;
        merged[(size_t)bl * CMERG + k] = p;
    }
    __syncthreads();
    size_t base = (size_t)bl * CMERG;
    for (int idx = tid; idx < FLAT; idx += 256) {
        int k = idx >> 6;
        float kv = zc[idx >> 3];     // k*8+h
        float th = theta[idx];
        float phi = kv * th;
        float s, c;
        __sincosf(phi, &s, &c);
        float p = pw[k];
        merged[base + KK + idx] = p * c;
        merged[base + KK + FLAT + idx] = p * s;
    }
}

// ---------------- chunked cumsum over l, per (b, channel) ----------------
__global__ __launch_bounds__(256) void scan_pass1(const float* __restrict__ merged,
                                                  float* __restrict__ partials) {
    int c = blockIdx.x * 256 + threadIdx.x;
    int chunk = blockIdx.y;
    int b = blockIdx.z;
    if (c >= CMERG) return;
    size_t base = ((size_t)b * LL + (size_t)chunk * CHUNK) * CMERG + c;
    float s = 0.f;
    for (int i = 0; i < CHUNK; ++i) s += merged[base + (size_t)i * CMERG];
    partials[((size_t)b * NCHUNK + chunk) * CMERG + c] = s;
}

__global__ __launch_bounds__(256) void scan_pass2(float* __restrict__ partials) {
    int idx = blockIdx.x * 256 + threadIdx.x;
    if (idx >= BB * CMERG) return;
    int b = idx / CMERG;
    int c = idx % CMERG;
    float run = 0.f;
    for (int ch = 0; ch < NCHUNK; ++ch) {
        size_t p = ((size_t)b * NCHUNK + ch) * CMERG + c;
        float v = partials[p];
        partials[p] = run;      // exclusive
        run += v;
    }
}

__global__ __launch_bounds__(256) void scan_pass3(float* __restrict__ merged,
                                                  const float* __restrict__ partials) {
    int c = blockIdx.x * 256 + threadIdx.x;
    int chunk = blockIdx.y;
    int b = blockIdx.z;
    if (c >= CMERG) return;
    float run = partials[((size_t)b * NCHUNK + chunk) * CMERG + c];
    size_t base = ((size_t)b * LL + (size_t)chunk * CHUNK) * CMERG + c;
    for (int i = 0; i < CHUNK; ++i) {
        size_t p = base + (size_t)i * CMERG;
        run += merged[p];
        merged[p] = run;        // in-place inclusive cumsum
    }
}

// ---------------- state -> out_re/out_im -> per-k einsum -> swiglu -> y (bf16) ----------------
__global__ __launch_bounds__(256) void stage_d(const float* __restrict__ cs,
                                               const unsigned short* __restrict__ zq,
                                               const float* __restrict__ W_re,
                                               const float* __restrict__ W_im,
                                               const float* __restrict__ nscale,
                                               unsigned short* __restrict__ y_act) {
    int bl = blockIdx.x;
    int tid = threadIdx.x;
    __shared__ float csh[CMERG];
    __shared__ float qh[NQ];
    __shared__ float ore[256];
    __shared__ float oim[256];
    __shared__ float yh[KK * 48];

    size_t cbase = (size_t)bl * CMERG;
    for (int i = tid; i < CMERG; i += 256) csh[i] = cs[cbase + i];
    for (int i = tid; i < NQ; i += 256) qh[i] = b2f(zq[(size_t)bl * ZSTR + CTOT + i]);
    __syncthreads();

    {
        int k = tid >> 3;
        int h = tid & 7;
        float den = fmaxf(csh[k], 1e-4f);
        float inv = 1.f / den;
        int kq = k >> 3;     // repeat factor 8
        float o_re = 0.f, o_im = 0.f;
#pragma unroll
        for (int m = 0; m < 8; ++m) {
            float sre = csh[KK + (tid << 3) + m] * inv;
            float sim = csh[KK + FLAT + (tid << 3) + m] * inv;
            float qre = qh[((kq * 8 + h) * 8 + m) * 2 + 0];
            float qim = qh[((kq * 8 + h) * 8 + m) * 2 + 1];
            o_re += sre * qre + sim * qim;
            o_im += sim * qre - sre * qim;
        }
        float ns = nscale[tid];
        ore[tid] = o_re * ns;
        oim[tid] = o_im * ns;
    }
    __syncthreads();

    for (int idx = tid; idx < KK * 48; idx += 256) {
        int k = idx / 48;
        int n = idx % 48;
        float acc = 0.f;
#pragma unroll
        for (int h = 0; h < 8; ++h) {
            int kh = k * 8 + h;
            acc += ore[kh] * W_re[kh * 48 + n] + oim[kh] * W_im[kh * 48 + n];
        }
        yh[idx] = acc;
    }
    __syncthreads();

    for (int idx = tid; idx < YDIM; idx += 256) {
        int k = idx / 24;
        int n = idx % 24;
        float v = yh[k * 48 + n];
        float gg = yh[k * 48 + 24 + n];
        float sg = gg / (1.f + expf(-gg));
        y_act[(size_t)bl * YDIM + idx] = f2b(v * sg);
    }
}

extern "C" void kernel_launch(void* const* d_in, const int* in_sizes, int n_in,
                              void* d_out, int out_size, void* d_ws, size_t ws_size,
                              hipStream_t stream) {
    const float* x      = (const float*)d_in[0];
    const float* W_mem  = (const float*)d_in[1];
    const float* conv_k = (const float*)d_in[2];
    const float* W_q    = (const float*)d_in[3];
    const float* theta  = (const float*)d_in[4];
    const float* decay  = (const float*)d_in[5];
    const float* anchor = (const float*)d_in[6];
    const float* sscale = (const float*)d_in[7];
    const float* W_re   = (const float*)d_in[8];
    const float* W_im   = (const float*)d_in[9];
    const float* nscale = (const float*)d_in[10];
    const float* W_out  = (const float*)d_in[11];
    float* out = (float*)d_out;
    float* ws = (float*)d_ws;

    // ---- d_out stash (all dead before final GEMM overwrites d_out) ----
    unsigned short* xb = (unsigned short*)out;                 // 16,777,216 bf16 (8,388,608 slots)
    unsigned short* Wb = (unsigned short*)(out + 8388608);     // 896*2048 bf16  (917,504 slots)
    unsigned short* zq = (unsigned short*)(out + 9306112);     // 8192*800 bf16  (3,276,800 slots) -> end 12,582,912
    // ---- ws ----
    float* merged   = ws;                                      // 33,816,576
    float* partials = ws + 33816576;                           // 132,096
    unsigned short* yb   = (unsigned short*)(ws + 33948672);   // 8192*768 bf16 (3,145,728 slots)
    unsigned short* Wohi = (unsigned short*)(ws + 37094400);   // 2048*768 bf16 (786,432 slots)
    unsigned short* Wolo = (unsigned short*)(ws + 37880832);   // end 38,667,264 floats (154.7 MB)

    cvt_x<<<8192, 256, 0, stream>>>(x, xb);
    prep_wb<<<NPAD, 256, 0, stream>>>(W_mem, W_q, Wb);
    prep_wo<<<DD, 256, 0, stream>>>(W_out, Wohi, Wolo);

    // 1) zq = x @ [W_mem | W_q]   (8192 x 800 x 2048), bf16 out
    gemm_mfma<false, true><<<dim3(NPAD / 128, BL / 128), 256, 0, stream>>>(
        xb, Wb, (const unsigned short*)nullptr, zq, DD, ZSTR, ZSTR);
    // 2) conv + p_w + trig -> merged
    convmerge<<<BL, 256, 0, stream>>>(zq, conv_k, theta, decay, anchor, sscale, merged);
    // 3) cumsum over l
    scan_pass1<<<dim3((CMERG + 255) / 256, NCHUNK, BB), 256, 0, stream>>>(merged, partials);
    scan_pass2<<<dim3((BB * CMERG + 255) / 256), 256, 0, stream>>>(partials);
    scan_pass3<<<dim3((CMERG + 255) / 256, NCHUNK, BB), 256, 0, stream>>>(merged, partials);
    // 4) state/query contraction + einsum + swiglu -> y (bf16)
    stage_d<<<BL, 256, 0, stream>>>(merged, zq, W_re, W_im, nscale, yb);
    // 5) out = y @ (Wo_hi + Wo_lo)^T   (8192 x 2048 x 768), split-B for precision
    gemm_mfma<true, false><<<dim3(DD / 128, BL / 128), 256, 0, stream>>>(
        yb, Wohi, Wolo, out, YDIM, DD, DD);
}

// Round 4
// 215.557 us; speedup vs baseline: 7.4643x; 1.4413x over previous
//
#include <hip/hip_runtime.h>
#include <hip/hip_bf16.h>
#include <math.h>

// Problem constants
#define BB 2
#define LL 4096
#define DD 2048
#define KK 32
#define MEM 256          // K*H
#define CTOT 288         // MEM+K
#define NQ 512           // KQ*H*M*2
#define ZSTR 800         // CTOT + NQ (combined z|q GEMM output stride)
#define NPAD 896         // padded N for combined GEMM (7*128)
#define FLAT 2048        // K*H*M
#define CMERG 4128       // K + 2*FLAT
#define CH 16            // scan chunk length
#define NCH 256          // L / CH
#define YDIM 768         // K*24
#define BL (BB*LL)       // 8192

typedef __attribute__((ext_vector_type(4))) float f32x4;
typedef __attribute__((ext_vector_type(8))) short bf16x8;
typedef __attribute__((ext_vector_type(8))) unsigned short u16x8;

__device__ inline unsigned short f2b(float v) {
    __hip_bfloat16 h = __float2bfloat16(v);
    return *reinterpret_cast<unsigned short*>(&h);
}
__device__ inline float b2f(unsigned short u) {
    __hip_bfloat16 h;
    *reinterpret_cast<unsigned short*>(&h) = u;
    return __bfloat162float(h);
}

__device__ inline void gload16(const void* g, void* l) {
    __builtin_amdgcn_global_load_lds(
        (const __attribute__((address_space(1))) unsigned int*)g,
        (__attribute__((address_space(3))) unsigned int*)l, 16, 0, 0);
}

// ---------------- converts / transposes ----------------
__global__ __launch_bounds__(256) void cvt_x(const float* __restrict__ x,
                                             unsigned short* __restrict__ xb) {
    size_t i = ((size_t)blockIdx.x * 256 + threadIdx.x) * 8;
    float4 a = *(const float4*)&x[i];
    float4 b = *(const float4*)&x[i + 4];
    u16x8 o;
    o[0] = f2b(a.x); o[1] = f2b(a.y); o[2] = f2b(a.z); o[3] = f2b(a.w);
    o[4] = f2b(b.x); o[5] = f2b(b.y); o[6] = f2b(b.z); o[7] = f2b(b.w);
    *(u16x8*)&xb[i] = o;
}

__global__ __launch_bounds__(256) void prep_wb(const float* __restrict__ W_mem,
                                               const float* __restrict__ W_q,
                                               unsigned short* __restrict__ Wb) {
    int n = blockIdx.x;   // 0..895
    for (int k = threadIdx.x; k < DD; k += 256) {
        float v = 0.f;
        if (n < CTOT) v = W_mem[(size_t)k * CTOT + n];
        else if (n < ZSTR) v = W_q[(size_t)k * NQ + (n - CTOT)];
        Wb[(size_t)n * DD + k] = f2b(v);
    }
}

__global__ __launch_bounds__(256) void prep_wo(const float* __restrict__ W_out,
                                               unsigned short* __restrict__ Whi,
                                               unsigned short* __restrict__ Wlo) {
    int n = blockIdx.x;   // 0..2047
    for (int k = threadIdx.x; k < YDIM; k += 256) {
        float v = W_out[(size_t)k * DD + n];
        unsigned short hi = f2b(v);
        float r = v - b2f(hi);
        Whi[(size_t)n * YDIM + k] = hi;
        Wlo[(size_t)n * YDIM + k] = f2b(r);
    }
}

// ---------------- bf16 MFMA GEMM: C[M,N] = A[M,K] * Bt[N,K]^T ----------------
template<bool SPLITB, bool CBF16>
__global__ __launch_bounds__(256) void gemm_mfma(const unsigned short* __restrict__ A,
                                                 const unsigned short* __restrict__ Bh_g,
                                                 const unsigned short* __restrict__ Bl_g,
                                                 void* __restrict__ Cout,
                                                 int Kd, int Nvalid, int Cstride) {
    __shared__ unsigned short As[4096];
    __shared__ unsigned short Bh[4096];
    __shared__ unsigned short Bl[SPLITB ? 4096 : 4];
    int tid = threadIdx.x;
    int lane = tid & 63;
    int wave = tid >> 6;
    int wr = wave >> 1, wc = wave & 1;
    int m0 = blockIdx.y * 128;
    int n0 = blockIdx.x * 128;

    f32x4 acc[4][4];
#pragma unroll
    for (int i = 0; i < 4; ++i)
#pragma unroll
        for (int j = 0; j < 4; ++j) acc[i][j] = (f32x4){0.f, 0.f, 0.f, 0.f};

    int f0 = tid, f1 = 256 + tid;
    int row0 = f0 >> 2, ks0 = (f0 & 3) ^ ((row0 >> 1) & 3);
    int row1 = f1 >> 2, ks1 = (f1 & 3) ^ ((row1 >> 1) & 3);
    const unsigned short* ga0 = &A[(size_t)(m0 + row0) * Kd + ks0 * 8];
    const unsigned short* ga1 = &A[(size_t)(m0 + row1) * Kd + ks1 * 8];
    const unsigned short* gb0 = &Bh_g[(size_t)(n0 + row0) * Kd + ks0 * 8];
    const unsigned short* gb1 = &Bh_g[(size_t)(n0 + row1) * Kd + ks1 * 8];
    const unsigned short* gl0 = SPLITB ? &Bl_g[(size_t)(n0 + row0) * Kd + ks0 * 8] : nullptr;
    const unsigned short* gl1 = SPLITB ? &Bl_g[(size_t)(n0 + row1) * Kd + ks1 * 8] : nullptr;
    int l0 = (wave * 64) * 8;
    int l1 = (256 + wave * 64) * 8;

    int g = lane >> 4, rr = lane & 15;

    for (int k0 = 0; k0 < Kd; k0 += 32) {
        if (k0) __syncthreads();
        gload16(ga0 + k0, &As[l0]);
        gload16(ga1 + k0, &As[l1]);
        gload16(gb0 + k0, &Bh[l0]);
        gload16(gb1 + k0, &Bh[l1]);
        if (SPLITB) {
            gload16(gl0 + k0, &Bl[l0]);
            gload16(gl1 + k0, &Bl[l1]);
        }
        __syncthreads();

        bf16x8 av[4], bhv[4], blv[4];
#pragma unroll
        for (int i = 0; i < 4; ++i) {
            int ra = wr * 64 + i * 16 + rr;
            av[i] = *(const bf16x8*)&As[ra * 32 + ((g ^ ((ra >> 1) & 3)) * 8)];
            int rb = wc * 64 + i * 16 + rr;
            int ob = rb * 32 + ((g ^ ((rb >> 1) & 3)) * 8);
            bhv[i] = *(const bf16x8*)&Bh[ob];
            if (SPLITB) blv[i] = *(const bf16x8*)&Bl[ob];
        }
#pragma unroll
        for (int i = 0; i < 4; ++i)
#pragma unroll
            for (int j = 0; j < 4; ++j) {
                acc[i][j] = __builtin_amdgcn_mfma_f32_16x16x32_bf16(av[i], bhv[j], acc[i][j], 0, 0, 0);
                if (SPLITB)
                    acc[i][j] = __builtin_amdgcn_mfma_f32_16x16x32_bf16(av[i], blv[j], acc[i][j], 0, 0, 0);
            }
    }

    int cg = lane >> 4, cr = lane & 15;
#pragma unroll
    for (int i = 0; i < 4; ++i)
#pragma unroll
        for (int j = 0; j < 4; ++j) {
            int colb = n0 + wc * 64 + j * 16 + cr;
            if (colb < Nvalid) {
#pragma unroll
                for (int r = 0; r < 4; ++r) {
                    int rowb = m0 + wr * 64 + i * 16 + cg * 4 + r;
                    if (CBF16)
                        ((unsigned short*)Cout)[(size_t)rowb * Cstride + colb] = f2b(acc[i][j][r]);
                    else
                        ((float*)Cout)[(size_t)rowb * Cstride + colb] = acc[i][j][r];
                }
            }
        }
}

// ---------------- fused A: conv+trig chunk partial sums (no merged buffer) ----------------
__global__ __launch_bounds__(256) void fused_partial(const unsigned short* __restrict__ zq,
                                                     const float* __restrict__ conv_k,
                                                     const float* __restrict__ theta,
                                                     const float* __restrict__ decay,
                                                     const float* __restrict__ anchor,
                                                     const float* __restrict__ sscale,
                                                     float* __restrict__ partials) {
    int chunk = blockIdx.x, b = blockIdx.y, t = threadIdx.x;
    int l0 = chunk * CH;
    __shared__ float zin[CH + 3][CTOT];
    __shared__ float pL[CH][KK];

    for (int idx = t; idx < (CH + 3) * CTOT; idx += 256) {
        int r = idx / CTOT, c = idx % CTOT;
        int l = l0 - 3 + r;
        zin[r][c] = (l >= 0) ? b2f(zq[(size_t)(b * LL + l) * ZSTR + c]) : 0.f;
    }
    __syncthreads();

    if (t < KK) {
        int k = t;
        float xx = (k < KK - 4) ? decay[k] : anchor[k - (KK - 4)];
        float sp = (xx > 20.f) ? xx : log1pf(expf(xx));
        float ss = sscale[k];
        float c0 = conv_k[0 * CTOT + MEM + k], c1 = conv_k[1 * CTOT + MEM + k];
        float c2 = conv_k[2 * CTOT + MEM + k], c3 = conv_k[3 * CTOT + MEM + k];
#pragma unroll
        for (int i = 0; i < CH; ++i) {
            float s = zin[i][MEM + k] * c0 + zin[i + 1][MEM + k] * c1 +
                      zin[i + 2][MEM + k] * c2 + zin[i + 3][MEM + k] * c3;
            int l = l0 + i;
            float lw = (k < KK - 4) ? -sp * (float)(LL - 1 - l) : -sp * (float)l;
            float lp = fminf(fmaxf(ss * s, -20.f), 20.f);
            pL[i][k] = expf(lp + lw);
        }
    }
    __syncthreads();

    float c0 = conv_k[0 * CTOT + t], c1 = conv_k[1 * CTOT + t];
    float c2 = conv_k[2 * CTOT + t], c3 = conv_k[3 * CTOT + t];
    float th[8];
#pragma unroll
    for (int m = 0; m < 8; ++m) th[m] = theta[t * 8 + m];
    float rs[8], is[8];
#pragma unroll
    for (int m = 0; m < 8; ++m) { rs[m] = 0.f; is[m] = 0.f; }
    int k = t >> 3;
#pragma unroll
    for (int i = 0; i < CH; ++i) {
        float kv = zin[i][t] * c0 + zin[i + 1][t] * c1 + zin[i + 2][t] * c2 + zin[i + 3][t] * c3;
        float p = pL[i][k];
#pragma unroll
        for (int m = 0; m < 8; ++m) {
            float sn, cn;
            __sincosf(kv * th[m], &sn, &cn);
            rs[m] += p * cn;
            is[m] += p * sn;
        }
    }
    size_t base = ((size_t)b * NCH + chunk) * CMERG;
#pragma unroll
    for (int m = 0; m < 8; ++m) {
        partials[base + KK + t * 8 + m] = rs[m];
        partials[base + KK + FLAT + t * 8 + m] = is[m];
    }
    if (t < KK) {
        float d = 0.f;
#pragma unroll
        for (int i = 0; i < CH; ++i) d += pL[i][t];
        partials[base + t] = d;
    }
}

// ---------------- fused B: exclusive scan of chunk partials (in place) ----------------
__global__ __launch_bounds__(256) void scan_partials(float* __restrict__ partials) {
    int t = threadIdx.x;
    int cl = t & 15, j = t >> 4;
    int c = blockIdx.x * 16 + cl;
    int b = blockIdx.y;
    float v[16];
    float s = 0.f;
#pragma unroll
    for (int i = 0; i < 16; ++i) {
        v[i] = partials[((size_t)b * NCH + j * 16 + i) * CMERG + c];
        s += v[i];
    }
    __shared__ float sums[16][17];
    sums[j][cl] = s;
    __syncthreads();
    if (j == 0) {
        float run = 0.f;
#pragma unroll
        for (int jj = 0; jj < 16; ++jj) {
            float x = sums[jj][cl];
            sums[jj][cl] = run;
            run += x;
        }
    }
    __syncthreads();
    float run = sums[j][cl];
#pragma unroll
    for (int i = 0; i < 16; ++i) {
        float x = v[i];
        partials[((size_t)b * NCH + j * 16 + i) * CMERG + c] = run;
        run += x;
    }
}

// ---------------- fused C: recompute + in-register scan + stage_d ----------------
__global__ __launch_bounds__(256) void fused_stage(const unsigned short* __restrict__ zq,
                                                   const float* __restrict__ conv_k,
                                                   const float* __restrict__ theta,
                                                   const float* __restrict__ decay,
                                                   const float* __restrict__ anchor,
                                                   const float* __restrict__ sscale,
                                                   const float* __restrict__ partials,
                                                   const float* __restrict__ W_re,
                                                   const float* __restrict__ W_im,
                                                   const float* __restrict__ nscale,
                                                   unsigned short* __restrict__ y_act) {
    int chunk = blockIdx.x, b = blockIdx.y, t = threadIdx.x;
    int l0 = chunk * CH;
    __shared__ float zin[CH + 3][CTOT];
    __shared__ float qall[CH][NQ];
    __shared__ float pL[CH][KK];
    __shared__ float dL[CH][KK];
    __shared__ float ore[256];
    __shared__ float oim[256];
    __shared__ float yh[KK * 48];

    for (int idx = t; idx < (CH + 3) * CTOT; idx += 256) {
        int r = idx / CTOT, c = idx % CTOT;
        int l = l0 - 3 + r;
        zin[r][c] = (l >= 0) ? b2f(zq[(size_t)(b * LL + l) * ZSTR + c]) : 0.f;
    }
    for (int idx = t; idx < CH * NQ; idx += 256) {
        int i = idx >> 9, c = idx & 511;
        qall[i][c] = b2f(zq[(size_t)(b * LL + l0 + i) * ZSTR + CTOT + c]);
    }
    __syncthreads();

    size_t pbase = ((size_t)b * NCH + chunk) * CMERG;
    if (t < KK) {
        int k = t;
        float xx = (k < KK - 4) ? decay[k] : anchor[k - (KK - 4)];
        float sp = (xx > 20.f) ? xx : log1pf(expf(xx));
        float ss = sscale[k];
        float c0 = conv_k[0 * CTOT + MEM + k], c1 = conv_k[1 * CTOT + MEM + k];
        float c2 = conv_k[2 * CTOT + MEM + k], c3 = conv_k[3 * CTOT + MEM + k];
        float run = partials[pbase + k];   // exclusive den offset
#pragma unroll
        for (int i = 0; i < CH; ++i) {
            float s = zin[i][MEM + k] * c0 + zin[i + 1][MEM + k] * c1 +
                      zin[i + 2][MEM + k] * c2 + zin[i + 3][MEM + k] * c3;
            int l = l0 + i;
            float lw = (k < KK - 4) ? -sp * (float)(LL - 1 - l) : -sp * (float)l;
            float lp = fminf(fmaxf(ss * s, -20.f), 20.f);
            float p = expf(lp + lw);
            run += p;
            pL[i][k] = p;
            dL[i][k] = run;
        }
    }

    // register state init from exclusive partials
    float rs[8], is[8];
#pragma unroll
    for (int m = 0; m < 8; ++m) {
        rs[m] = partials[pbase + KK + t * 8 + m];
        is[m] = partials[pbase + KK + FLAT + t * 8 + m];
    }
    float c0 = conv_k[0 * CTOT + t], c1 = conv_k[1 * CTOT + t];
    float c2 = conv_k[2 * CTOT + t], c3 = conv_k[3 * CTOT + t];
    float th[8];
#pragma unroll
    for (int m = 0; m < 8; ++m) th[m] = theta[t * 8 + m];
    float ns = nscale[t];
    int k = t >> 3, h = t & 7, kq = t >> 6;
    int qb = kq * 128 + h * 16;

    // hoist W_re/W_im for this thread's 6 einsum outputs
    float wre[6][8], wim[6][8];
    int ko[6], no[6];
#pragma unroll
    for (int jj = 0; jj < 6; ++jj) {
        int o = t + jj * 256;
        ko[jj] = o / 48;
        no[jj] = o % 48;
#pragma unroll
        for (int hh = 0; hh < 8; ++hh) {
            wre[jj][hh] = W_re[(ko[jj] * 8 + hh) * 48 + no[jj]];
            wim[jj][hh] = W_im[(ko[jj] * 8 + hh) * 48 + no[jj]];
        }
    }
    __syncthreads();   // pL/dL ready

#pragma unroll 1
    for (int i = 0; i < CH; ++i) {
        float kv = zin[i][t] * c0 + zin[i + 1][t] * c1 + zin[i + 2][t] * c2 + zin[i + 3][t] * c3;
        float p = pL[i][k];
#pragma unroll
        for (int m = 0; m < 8; ++m) {
            float sn, cn;
            __sincosf(kv * th[m], &sn, &cn);
            rs[m] += p * cn;
            is[m] += p * sn;
        }
        float inv = 1.f / fmaxf(dL[i][k], 1e-4f);
        float o_re = 0.f, o_im = 0.f;
#pragma unroll
        for (int m = 0; m < 8; ++m) {
            float sre = rs[m] * inv;
            float sim = is[m] * inv;
            float qre = qall[i][qb + m * 2 + 0];
            float qim = qall[i][qb + m * 2 + 1];
            o_re += sre * qre + sim * qim;
            o_im += sim * qre - sre * qim;
        }
        ore[t] = o_re * ns;
        oim[t] = o_im * ns;
        __syncthreads();

#pragma unroll
        for (int jj = 0; jj < 6; ++jj) {
            float acc = 0.f;
#pragma unroll
            for (int hh = 0; hh < 8; ++hh) {
                int kh = ko[jj] * 8 + hh;
                acc += ore[kh] * wre[jj][hh] + oim[kh] * wim[jj][hh];
            }
            yh[t + jj * 256] = acc;
        }
        __syncthreads();

        size_t ybase = (size_t)(b * LL + l0 + i) * YDIM;
#pragma unroll
        for (int jj = 0; jj < 3; ++jj) {
            int idx = t + jj * 256;
            int kk2 = idx / 24, nn = idx % 24;
            float v = yh[kk2 * 48 + nn];
            float gg = yh[kk2 * 48 + 24 + nn];
            float sg = gg / (1.f + expf(-gg));
            y_act[ybase + idx] = f2b(v * sg);
        }
        __syncthreads();
    }
}

extern "C" void kernel_launch(void* const* d_in, const int* in_sizes, int n_in,
                              void* d_out, int out_size, void* d_ws, size_t ws_size,
                              hipStream_t stream) {
    const float* x      = (const float*)d_in[0];
    const float* W_mem  = (const float*)d_in[1];
    const float* conv_k = (const float*)d_in[2];
    const float* W_q    = (const float*)d_in[3];
    const float* theta  = (const float*)d_in[4];
    const float* decay  = (const float*)d_in[5];
    const float* anchor = (const float*)d_in[6];
    const float* sscale = (const float*)d_in[7];
    const float* W_re   = (const float*)d_in[8];
    const float* W_im   = (const float*)d_in[9];
    const float* nscale = (const float*)d_in[10];
    const float* W_out  = (const float*)d_in[11];
    float* out = (float*)d_out;
    float* ws = (float*)d_ws;

    // ---- d_out stash (dead before final GEMM writes d_out) ----
    unsigned short* xb = (unsigned short*)out;                 // 16,777,216 bf16 -> 8,388,608 float slots
    unsigned short* Wb = (unsigned short*)(out + 8388608);     // 896*2048 bf16 -> 917,504 slots
    unsigned short* zq = (unsigned short*)(out + 9306112);     // 8192*800 bf16 -> 3,276,800 slots, ends 12,582,912
    // ---- ws (offsets in float slots; bf16 count / 2 = float slots) ----
    float* partials      = ws;                                 // 2*256*4128 = 2,113,536 floats
    unsigned short* yb   = (unsigned short*)(ws + 2113536);    // 8192*768 bf16 = 3,145,728 float slots
    unsigned short* Wohi = (unsigned short*)(ws + 5259264);    // 2048*768 bf16 = 786,432 float slots
    unsigned short* Wolo = (unsigned short*)(ws + 6045696);    // ends 6,832,128 floats (27.3 MB)

    cvt_x<<<8192, 256, 0, stream>>>(x, xb);
    prep_wb<<<NPAD, 256, 0, stream>>>(W_mem, W_q, Wb);
    prep_wo<<<DD, 256, 0, stream>>>(W_out, Wohi, Wolo);

    // 1) zq = x @ [W_mem | W_q]   (8192 x 800 x 2048), bf16 out
    gemm_mfma<false, true><<<dim3(NPAD / 128, BL / 128), 256, 0, stream>>>(
        xb, Wb, (const unsigned short*)nullptr, zq, DD, ZSTR, ZSTR);
    // 2) chunk partial sums (conv+trig recompute, registers only)
    fused_partial<<<dim3(NCH, BB), 256, 0, stream>>>(zq, conv_k, theta, decay, anchor, sscale, partials);
    // 3) exclusive scan of chunk partials
    scan_partials<<<dim3(CMERG / 16, BB), 256, 0, stream>>>(partials);
    // 4) recompute + in-register inclusive scan + fused stage_d -> y (bf16)
    fused_stage<<<dim3(NCH, BB), 256, 0, stream>>>(zq, conv_k, theta, decay, anchor, sscale,
                                                   partials, W_re, W_im, nscale, yb);
    // 5) out = y @ (Wo_hi + Wo_lo)^T   (8192 x 2048 x 768), split-B for precision
    gemm_mfma<true, false><<<dim3(DD / 128, BL / 128), 256, 0, stream>>>(
        yb, Wohi, Wolo, out, YDIM, DD, DD);
}

// Round 5
// 198.942 us; speedup vs baseline: 8.0877x; 1.0835x over previous
//
#include <hip/hip_runtime.h>
#include <hip/hip_bf16.h>
#include <math.h>

// Problem constants
#define BB 2
#define LL 4096
#define DD 2048
#define KK 32
#define MEM 256          // K*H
#define CTOT 288         // MEM+K
#define NQ 512           // KQ*H*M*2
#define ZSTR 800         // CTOT + NQ (combined z|q GEMM output stride)
#define NPAD 896         // padded N for combined GEMM (7*128)
#define FLAT 2048        // K*H*M
#define CMERG 4128       // K + 2*FLAT
#define CH 16            // scan chunk length
#define NCH 256          // L / CH
#define YDIM 768         // K*24
#define BL (BB*LL)       // 8192

typedef __attribute__((ext_vector_type(4))) float f32x4;
typedef __attribute__((ext_vector_type(8))) short bf16x8;
typedef __attribute__((ext_vector_type(8))) unsigned short u16x8;

__device__ inline unsigned short f2b(float v) {
    __hip_bfloat16 h = __float2bfloat16(v);
    return *reinterpret_cast<unsigned short*>(&h);
}
__device__ inline float b2f(unsigned short u) {
    __hip_bfloat16 h;
    *reinterpret_cast<unsigned short*>(&h) = u;
    return __bfloat162float(h);
}

__device__ inline void gload16(const void* g, void* l) {
    __builtin_amdgcn_global_load_lds(
        (const __attribute__((address_space(1))) unsigned int*)g,
        (__attribute__((address_space(3))) unsigned int*)l, 16, 0, 0);
}

// broadcast lane (group_base | HH) within aligned 8-lane groups (BitMode swizzle)
template<int HH>
__device__ inline float bcast8(float v) {
    return __int_as_float(__builtin_amdgcn_ds_swizzle(__float_as_int(v), (HH << 5) | 0x18));
}

// ---------------- converts / transposes ----------------
__global__ __launch_bounds__(256) void cvt_x(const float* __restrict__ x,
                                             unsigned short* __restrict__ xb) {
    size_t i = ((size_t)blockIdx.x * 256 + threadIdx.x) * 8;
    float4 a = *(const float4*)&x[i];
    float4 b = *(const float4*)&x[i + 4];
    u16x8 o;
    o[0] = f2b(a.x); o[1] = f2b(a.y); o[2] = f2b(a.z); o[3] = f2b(a.w);
    o[4] = f2b(b.x); o[5] = f2b(b.y); o[6] = f2b(b.z); o[7] = f2b(b.w);
    *(u16x8*)&xb[i] = o;
}

__global__ __launch_bounds__(256) void prep_wb(const float* __restrict__ W_mem,
                                               const float* __restrict__ W_q,
                                               unsigned short* __restrict__ Wb) {
    int n = blockIdx.x;   // 0..895
    for (int k = threadIdx.x; k < DD; k += 256) {
        float v = 0.f;
        if (n < CTOT) v = W_mem[(size_t)k * CTOT + n];
        else if (n < ZSTR) v = W_q[(size_t)k * NQ + (n - CTOT)];
        Wb[(size_t)n * DD + k] = f2b(v);
    }
}

__global__ __launch_bounds__(256) void prep_wo(const float* __restrict__ W_out,
                                               unsigned short* __restrict__ Whi,
                                               unsigned short* __restrict__ Wlo) {
    int n = blockIdx.x;   // 0..2047
    for (int k = threadIdx.x; k < YDIM; k += 256) {
        float v = W_out[(size_t)k * DD + n];
        unsigned short hi = f2b(v);
        float r = v - b2f(hi);
        Whi[(size_t)n * YDIM + k] = hi;
        Wlo[(size_t)n * YDIM + k] = f2b(r);
    }
}

// ---------------- bf16 MFMA GEMM: C[M,N] = A[M,K] * Bt[N,K]^T ----------------
template<bool SPLITB, bool CBF16>
__global__ __launch_bounds__(256) void gemm_mfma(const unsigned short* __restrict__ A,
                                                 const unsigned short* __restrict__ Bh_g,
                                                 const unsigned short* __restrict__ Bl_g,
                                                 void* __restrict__ Cout,
                                                 int Kd, int Nvalid, int Cstride) {
    __shared__ unsigned short As[4096];
    __shared__ unsigned short Bh[4096];
    __shared__ unsigned short Bl[SPLITB ? 4096 : 4];
    int tid = threadIdx.x;
    int lane = tid & 63;
    int wave = tid >> 6;
    int wr = wave >> 1, wc = wave & 1;
    int m0 = blockIdx.y * 128;
    int n0 = blockIdx.x * 128;

    f32x4 acc[4][4];
#pragma unroll
    for (int i = 0; i < 4; ++i)
#pragma unroll
        for (int j = 0; j < 4; ++j) acc[i][j] = (f32x4){0.f, 0.f, 0.f, 0.f};

    int f0 = tid, f1 = 256 + tid;
    int row0 = f0 >> 2, ks0 = (f0 & 3) ^ ((row0 >> 1) & 3);
    int row1 = f1 >> 2, ks1 = (f1 & 3) ^ ((row1 >> 1) & 3);
    const unsigned short* ga0 = &A[(size_t)(m0 + row0) * Kd + ks0 * 8];
    const unsigned short* ga1 = &A[(size_t)(m0 + row1) * Kd + ks1 * 8];
    const unsigned short* gb0 = &Bh_g[(size_t)(n0 + row0) * Kd + ks0 * 8];
    const unsigned short* gb1 = &Bh_g[(size_t)(n0 + row1) * Kd + ks1 * 8];
    const unsigned short* gl0 = SPLITB ? &Bl_g[(size_t)(n0 + row0) * Kd + ks0 * 8] : nullptr;
    const unsigned short* gl1 = SPLITB ? &Bl_g[(size_t)(n0 + row1) * Kd + ks1 * 8] : nullptr;
    int l0 = (wave * 64) * 8;
    int l1 = (256 + wave * 64) * 8;

    int g = lane >> 4, rr = lane & 15;

    for (int k0 = 0; k0 < Kd; k0 += 32) {
        if (k0) __syncthreads();
        gload16(ga0 + k0, &As[l0]);
        gload16(ga1 + k0, &As[l1]);
        gload16(gb0 + k0, &Bh[l0]);
        gload16(gb1 + k0, &Bh[l1]);
        if (SPLITB) {
            gload16(gl0 + k0, &Bl[l0]);
            gload16(gl1 + k0, &Bl[l1]);
        }
        __syncthreads();

        bf16x8 av[4], bhv[4], blv[4];
#pragma unroll
        for (int i = 0; i < 4; ++i) {
            int ra = wr * 64 + i * 16 + rr;
            av[i] = *(const bf16x8*)&As[ra * 32 + ((g ^ ((ra >> 1) & 3)) * 8)];
            int rb = wc * 64 + i * 16 + rr;
            int ob = rb * 32 + ((g ^ ((rb >> 1) & 3)) * 8);
            bhv[i] = *(const bf16x8*)&Bh[ob];
            if (SPLITB) blv[i] = *(const bf16x8*)&Bl[ob];
        }
#pragma unroll
        for (int i = 0; i < 4; ++i)
#pragma unroll
            for (int j = 0; j < 4; ++j) {
                acc[i][j] = __builtin_amdgcn_mfma_f32_16x16x32_bf16(av[i], bhv[j], acc[i][j], 0, 0, 0);
                if (SPLITB)
                    acc[i][j] = __builtin_amdgcn_mfma_f32_16x16x32_bf16(av[i], blv[j], acc[i][j], 0, 0, 0);
            }
    }

    int cg = lane >> 4, cr = lane & 15;
#pragma unroll
    for (int i = 0; i < 4; ++i)
#pragma unroll
        for (int j = 0; j < 4; ++j) {
            int colb = n0 + wc * 64 + j * 16 + cr;
            if (colb < Nvalid) {
#pragma unroll
                for (int r = 0; r < 4; ++r) {
                    int rowb = m0 + wr * 64 + i * 16 + cg * 4 + r;
                    if (CBF16)
                        ((unsigned short*)Cout)[(size_t)rowb * Cstride + colb] = f2b(acc[i][j][r]);
                    else
                        ((float*)Cout)[(size_t)rowb * Cstride + colb] = acc[i][j][r];
                }
            }
        }
}

// ---------------- fused A: conv+trig chunk partial sums (barrier-free main loop) ----------------
// thread t owns kh-channel t; 8-lane group = one k; p/den computed redundantly per group.
__global__ __launch_bounds__(256) void fused_partial(const unsigned short* __restrict__ zq,
                                                     const float* __restrict__ conv_k,
                                                     const float* __restrict__ theta,
                                                     const float* __restrict__ decay,
                                                     const float* __restrict__ anchor,
                                                     const float* __restrict__ sscale,
                                                     float* __restrict__ partials) {
    int chunk = blockIdx.x, b = blockIdx.y, t = threadIdx.x;
    int l0 = chunk * CH;
    __shared__ unsigned short zin[CH + 3][CTOT];

    for (int idx = t; idx < (CH + 3) * 36; idx += 256) {
        int r = idx / 36, c8 = (idx % 36) * 8;
        int l = l0 - 3 + r;
        u16x8 v = (u16x8)(0);
        if (l >= 0) v = *(const u16x8*)&zq[(size_t)(b * LL + l) * ZSTR + c8];
        *(u16x8*)&zin[r][c8] = v;
    }
    __syncthreads();

    int k = t >> 3;
    float cz0 = conv_k[t], cz1 = conv_k[CTOT + t], cz2 = conv_k[2 * CTOT + t], cz3 = conv_k[3 * CTOT + t];
    int sc = MEM + k;
    float cs0 = conv_k[sc], cs1 = conv_k[CTOT + sc], cs2 = conv_k[2 * CTOT + sc], cs3 = conv_k[3 * CTOT + sc];
    float xx = (k < KK - 4) ? decay[k] : anchor[k - (KK - 4)];
    float sp = (xx > 20.f) ? xx : log1pf(expf(xx));
    float ss = sscale[k];
    float th[8];
#pragma unroll
    for (int m = 0; m < 8; ++m) th[m] = theta[t * 8 + m];
    float rs[8], is[8];
#pragma unroll
    for (int m = 0; m < 8; ++m) { rs[m] = 0.f; is[m] = 0.f; }
    float dsum = 0.f;

#pragma unroll 1
    for (int i = 0; i < CH; ++i) {
        float kv = b2f(zin[i][t]) * cz0 + b2f(zin[i + 1][t]) * cz1 +
                   b2f(zin[i + 2][t]) * cz2 + b2f(zin[i + 3][t]) * cz3;
        float s = b2f(zin[i][sc]) * cs0 + b2f(zin[i + 1][sc]) * cs1 +
                  b2f(zin[i + 2][sc]) * cs2 + b2f(zin[i + 3][sc]) * cs3;
        int l = l0 + i;
        float lw = (k < KK - 4) ? -sp * (float)(LL - 1 - l) : -sp * (float)l;
        float lp = fminf(fmaxf(ss * s, -20.f), 20.f);
        float p = expf(lp + lw);
        dsum += p;
#pragma unroll
        for (int m = 0; m < 8; ++m) {
            float sn, cn;
            __sincosf(kv * th[m], &sn, &cn);
            rs[m] += p * cn;
            is[m] += p * sn;
        }
    }
    size_t base = ((size_t)b * NCH + chunk) * CMERG;
    *(f32x4*)&partials[base + KK + t * 8]            = (f32x4){rs[0], rs[1], rs[2], rs[3]};
    *(f32x4*)&partials[base + KK + t * 8 + 4]        = (f32x4){rs[4], rs[5], rs[6], rs[7]};
    *(f32x4*)&partials[base + KK + FLAT + t * 8]     = (f32x4){is[0], is[1], is[2], is[3]};
    *(f32x4*)&partials[base + KK + FLAT + t * 8 + 4] = (f32x4){is[4], is[5], is[6], is[7]};
    if ((t & 7) == 0) partials[base + k] = dsum;
}

// ---------------- fused B: exclusive scan of chunk partials (in place) ----------------
__global__ __launch_bounds__(256) void scan_partials(float* __restrict__ partials) {
    int t = threadIdx.x;
    int cl = t & 15, j = t >> 4;
    int c = blockIdx.x * 16 + cl;
    int b = blockIdx.y;
    float v[16];
    float s = 0.f;
#pragma unroll
    for (int i = 0; i < 16; ++i) {
        v[i] = partials[((size_t)b * NCH + j * 16 + i) * CMERG + c];
        s += v[i];
    }
    __shared__ float sums[16][17];
    sums[j][cl] = s;
    __syncthreads();
    if (j == 0) {
        float run = 0.f;
#pragma unroll
        for (int jj = 0; jj < 16; ++jj) {
            float x = sums[jj][cl];
            sums[jj][cl] = run;
            run += x;
        }
    }
    __syncthreads();
    float run = sums[j][cl];
#pragma unroll
    for (int i = 0; i < 16; ++i) {
        float x = v[i];
        partials[((size_t)b * NCH + j * 16 + i) * CMERG + c] = run;
        run += x;
    }
}

// ---------------- fused C: recompute + in-register scan + stage_d (barrier-free loop) ----------------
// wave w owns k in [8w, 8w+8); lane l: kloc=l>>3, h=l&7; einsum gathered via ds_swizzle.
__global__ __launch_bounds__(256) void fused_stage(const unsigned short* __restrict__ zq,
                                                   const float* __restrict__ conv_k,
                                                   const float* __restrict__ theta,
                                                   const float* __restrict__ decay,
                                                   const float* __restrict__ anchor,
                                                   const float* __restrict__ sscale,
                                                   const float* __restrict__ partials,
                                                   const float* __restrict__ W_re,
                                                   const float* __restrict__ W_im,
                                                   const float* __restrict__ nscale,
                                                   unsigned short* __restrict__ y_act) {
    int chunk = blockIdx.x, b = blockIdx.y, t = threadIdx.x;
    int l0 = chunk * CH;
    __shared__ unsigned short zin[CH + 3][CTOT];   // raw bf16 (zq is already bf16)
    __shared__ unsigned short qall[CH][NQ];

    for (int idx = t; idx < (CH + 3) * 36; idx += 256) {
        int r = idx / 36, c8 = (idx % 36) * 8;
        int l = l0 - 3 + r;
        u16x8 v = (u16x8)(0);
        if (l >= 0) v = *(const u16x8*)&zq[(size_t)(b * LL + l) * ZSTR + c8];
        *(u16x8*)&zin[r][c8] = v;
    }
    for (int idx = t; idx < CH * (NQ / 8); idx += 256) {
        int i = idx >> 6, c8 = (idx & 63) * 8;
        *(u16x8*)&qall[i][c8] = *(const u16x8*)&zq[(size_t)(b * LL + l0 + i) * ZSTR + CTOT + c8];
    }
    __syncthreads();

    int k = t >> 3, h = t & 7, w = t >> 6;
    float cz0 = conv_k[t], cz1 = conv_k[CTOT + t], cz2 = conv_k[2 * CTOT + t], cz3 = conv_k[3 * CTOT + t];
    int sc = MEM + k;
    float cs0 = conv_k[sc], cs1 = conv_k[CTOT + sc], cs2 = conv_k[2 * CTOT + sc], cs3 = conv_k[3 * CTOT + sc];
    float xx = (k < KK - 4) ? decay[k] : anchor[k - (KK - 4)];
    float sp = (xx > 20.f) ? xx : log1pf(expf(xx));
    float ss = sscale[k];
    float th[8];
#pragma unroll
    for (int m = 0; m < 8; ++m) th[m] = theta[t * 8 + m];
    float ns = nscale[t];
    int qb = w * 128 + h * 16;

    // einsum weights for this lane's 6 outputs: wre[hh][jj] for output n = h + 8*jj of row k
    float wre[8][6], wim[8][6];
#pragma unroll
    for (int hh = 0; hh < 8; ++hh)
#pragma unroll
        for (int jj = 0; jj < 6; ++jj) {
            wre[hh][jj] = W_re[(k * 8 + hh) * 48 + h + 8 * jj];
            wim[hh][jj] = W_im[(k * 8 + hh) * 48 + h + 8 * jj];
        }

    size_t pbase = ((size_t)b * NCH + chunk) * CMERG;
    f32x4 r0 = *(const f32x4*)&partials[pbase + KK + t * 8];
    f32x4 r1 = *(const f32x4*)&partials[pbase + KK + t * 8 + 4];
    f32x4 i0 = *(const f32x4*)&partials[pbase + KK + FLAT + t * 8];
    f32x4 i1 = *(const f32x4*)&partials[pbase + KK + FLAT + t * 8 + 4];
    float rs[8] = {r0[0], r0[1], r0[2], r0[3], r1[0], r1[1], r1[2], r1[3]};
    float is[8] = {i0[0], i0[1], i0[2], i0[3], i1[0], i1[1], i1[2], i1[3]};
    float den = partials[pbase + k];   // exclusive denominator offset

#pragma unroll 1
    for (int i = 0; i < CH; ++i) {
        float kv = b2f(zin[i][t]) * cz0 + b2f(zin[i + 1][t]) * cz1 +
                   b2f(zin[i + 2][t]) * cz2 + b2f(zin[i + 3][t]) * cz3;
        float s = b2f(zin[i][sc]) * cs0 + b2f(zin[i + 1][sc]) * cs1 +
                  b2f(zin[i + 2][sc]) * cs2 + b2f(zin[i + 3][sc]) * cs3;
        int l = l0 + i;
        float lw = (k < KK - 4) ? -sp * (float)(LL - 1 - l) : -sp * (float)l;
        float lp = fminf(fmaxf(ss * s, -20.f), 20.f);
        float p = expf(lp + lw);
        den += p;
        float inv = 1.f / fmaxf(den, 1e-4f);
#pragma unroll
        for (int m = 0; m < 8; ++m) {
            float sn, cn;
            __sincosf(kv * th[m], &sn, &cn);
            rs[m] += p * cn;
            is[m] += p * sn;
        }
        u16x8 qv0 = *(const u16x8*)&qall[i][qb];
        u16x8 qv1 = *(const u16x8*)&qall[i][qb + 8];
        float o_re = 0.f, o_im = 0.f;
#pragma unroll
        for (int m = 0; m < 8; ++m) {
            float sre = rs[m] * inv;
            float sim = is[m] * inv;
            float qre = b2f((unsigned short)((m < 4) ? qv0[2 * m] : qv1[2 * m - 8]));
            float qim = b2f((unsigned short)((m < 4) ? qv0[2 * m + 1] : qv1[2 * m - 7]));
            o_re += sre * qre + sim * qim;
            o_im += sim * qre - sre * qim;
        }
        o_re *= ns;
        o_im *= ns;

        // per-k einsum via intra-group broadcast (no LDS, no barrier)
        float y0 = 0.f, y1 = 0.f, y2 = 0.f, y3 = 0.f, y4 = 0.f, y5 = 0.f;
#define EAPPLY(HH) { float br_ = bcast8<HH>(o_re); float bi_ = bcast8<HH>(o_im); \
        y0 += br_ * wre[HH][0] + bi_ * wim[HH][0]; \
        y1 += br_ * wre[HH][1] + bi_ * wim[HH][1]; \
        y2 += br_ * wre[HH][2] + bi_ * wim[HH][2]; \
        y3 += br_ * wre[HH][3] + bi_ * wim[HH][3]; \
        y4 += br_ * wre[HH][4] + bi_ * wim[HH][4]; \
        y5 += br_ * wre[HH][5] + bi_ * wim[HH][5]; }
        EAPPLY(0) EAPPLY(1) EAPPLY(2) EAPPLY(3)
        EAPPLY(4) EAPPLY(5) EAPPLY(6) EAPPLY(7)
#undef EAPPLY

        // swiglu: outputs n = h+8*{0,1,2} (vals), gates at n+24 = h+8*{3,4,5}
        float sg0 = y3 / (1.f + expf(-y3));
        float sg1 = y4 / (1.f + expf(-y4));
        float sg2 = y5 / (1.f + expf(-y5));
        size_t ybase = (size_t)(b * LL + l) * YDIM + k * 24 + h;
        y_act[ybase]      = f2b(y0 * sg0);
        y_act[ybase + 8]  = f2b(y1 * sg1);
        y_act[ybase + 16] = f2b(y2 * sg2);
    }
}

extern "C" void kernel_launch(void* const* d_in, const int* in_sizes, int n_in,
                              void* d_out, int out_size, void* d_ws, size_t ws_size,
                              hipStream_t stream) {
    const float* x      = (const float*)d_in[0];
    const float* W_mem  = (const float*)d_in[1];
    const float* conv_k = (const float*)d_in[2];
    const float* W_q    = (const float*)d_in[3];
    const float* theta  = (const float*)d_in[4];
    const float* decay  = (const float*)d_in[5];
    const float* anchor = (const float*)d_in[6];
    const float* sscale = (const float*)d_in[7];
    const float* W_re   = (const float*)d_in[8];
    const float* W_im   = (const float*)d_in[9];
    const float* nscale = (const float*)d_in[10];
    const float* W_out  = (const float*)d_in[11];
    float* out = (float*)d_out;
    float* ws = (float*)d_ws;

    // ---- d_out stash (dead before final GEMM writes d_out) ----
    unsigned short* xb = (unsigned short*)out;                 // 16,777,216 bf16 -> 8,388,608 float slots
    unsigned short* Wb = (unsigned short*)(out + 8388608);     // 896*2048 bf16 -> 917,504 slots
    unsigned short* zq = (unsigned short*)(out + 9306112);     // 8192*800 bf16 -> 3,276,800 slots, ends 12,582,912
    // ---- ws (offsets in float slots) ----
    float* partials      = ws;                                 // 2*256*4128 = 2,113,536 floats
    unsigned short* yb   = (unsigned short*)(ws + 2113536);    // 8192*768 bf16 = 3,145,728 float slots
    unsigned short* Wohi = (unsigned short*)(ws + 5259264);    // 2048*768 bf16 = 786,432 float slots
    unsigned short* Wolo = (unsigned short*)(ws + 6045696);    // ends 6,832,128 floats (27.3 MB)

    cvt_x<<<8192, 256, 0, stream>>>(x, xb);
    prep_wb<<<NPAD, 256, 0, stream>>>(W_mem, W_q, Wb);
    prep_wo<<<DD, 256, 0, stream>>>(W_out, Wohi, Wolo);

    // 1) zq = x @ [W_mem | W_q]   (8192 x 800 x 2048), bf16 out
    gemm_mfma<false, true><<<dim3(NPAD / 128, BL / 128), 256, 0, stream>>>(
        xb, Wb, (const unsigned short*)nullptr, zq, DD, ZSTR, ZSTR);
    // 2) chunk partial sums (conv+trig recompute, registers only)
    fused_partial<<<dim3(NCH, BB), 256, 0, stream>>>(zq, conv_k, theta, decay, anchor, sscale, partials);
    // 3) exclusive scan of chunk partials
    scan_partials<<<dim3(CMERG / 16, BB), 256, 0, stream>>>(partials);
    // 4) recompute + in-register inclusive scan + fused stage_d -> y (bf16)
    fused_stage<<<dim3(NCH, BB), 256, 0, stream>>>(zq, conv_k, theta, decay, anchor, sscale,
                                                   partials, W_re, W_im, nscale, yb);
    // 5) out = y @ (Wo_hi + Wo_lo)^T   (8192 x 2048 x 768), split-B for precision
    gemm_mfma<true, false><<<dim3(DD / 128, BL / 128), 256, 0, stream>>>(
        yb, Wohi, Wolo, out, YDIM, DD, DD);
}

// Round 6
// 186.478 us; speedup vs baseline: 8.6283x; 1.0668x over previous
//
#include <hip/hip_runtime.h>
#include <hip/hip_bf16.h>
#include <math.h>

// Problem constants
#define BB 2
#define LL 4096
#define DD 2048
#define KK 32
#define MEM 256          // K*H
#define CTOT 288         // MEM+K
#define NQ 512           // KQ*H*M*2
#define ZSTR 800         // CTOT + NQ (combined z|q GEMM output stride)
#define NPAD 896         // padded N for combined GEMM (7*128)
#define FLAT 2048        // K*H*M
#define CMERG 4128       // K + 2*FLAT
#define CH 16            // scan chunk length
#define NCH 256          // L / CH
#define YDIM 768         // K*24
#define BL (BB*LL)       // 8192

typedef __attribute__((ext_vector_type(4))) float f32x4;
typedef __attribute__((ext_vector_type(8))) short bf16x8;
typedef __attribute__((ext_vector_type(8))) unsigned short u16x8;

__device__ inline unsigned short f2b(float v) {
    __hip_bfloat16 h = __float2bfloat16(v);
    return *reinterpret_cast<unsigned short*>(&h);
}
__device__ inline float b2f(unsigned short u) {
    __hip_bfloat16 h;
    *reinterpret_cast<unsigned short*>(&h) = u;
    return __bfloat162float(h);
}

__device__ inline void gload16(const void* g, void* l) {
    __builtin_amdgcn_global_load_lds(
        (const __attribute__((address_space(1))) unsigned int*)g,
        (__attribute__((address_space(3))) unsigned int*)l, 16, 0, 0);
}

// broadcast lane (group_base | HH) within aligned 8-lane groups (BitMode swizzle)
template<int HH>
__device__ inline float bcast8(float v) {
    return __int_as_float(__builtin_amdgcn_ds_swizzle(__float_as_int(v), (HH << 5) | 0x18));
}

__device__ inline float fast_sigmoid_mul(float val, float g) {
    // val * silu-gate's sigmoid: val * 1/(1+e^-g)
    return val * __builtin_amdgcn_rcpf(1.f + __expf(-g));
}

// ---------------- converts / transposes ----------------
__global__ __launch_bounds__(256) void cvt_x(const float* __restrict__ x,
                                             unsigned short* __restrict__ xb) {
    size_t i = ((size_t)blockIdx.x * 256 + threadIdx.x) * 8;
    float4 a = *(const float4*)&x[i];
    float4 b = *(const float4*)&x[i + 4];
    u16x8 o;
    o[0] = f2b(a.x); o[1] = f2b(a.y); o[2] = f2b(a.z); o[3] = f2b(a.w);
    o[4] = f2b(b.x); o[5] = f2b(b.y); o[6] = f2b(b.z); o[7] = f2b(b.w);
    *(u16x8*)&xb[i] = o;
}

__global__ __launch_bounds__(256) void prep_wb(const float* __restrict__ W_mem,
                                               const float* __restrict__ W_q,
                                               unsigned short* __restrict__ Wb) {
    int n = blockIdx.x;   // 0..895
    for (int k = threadIdx.x; k < DD; k += 256) {
        float v = 0.f;
        if (n < CTOT) v = W_mem[(size_t)k * CTOT + n];
        else if (n < ZSTR) v = W_q[(size_t)k * NQ + (n - CTOT)];
        Wb[(size_t)n * DD + k] = f2b(v);
    }
}

__global__ __launch_bounds__(256) void prep_wo(const float* __restrict__ W_out,
                                               unsigned short* __restrict__ Whi,
                                               unsigned short* __restrict__ Wlo) {
    int n = blockIdx.x;   // 0..2047
    for (int k = threadIdx.x; k < YDIM; k += 256) {
        float v = W_out[(size_t)k * DD + n];
        unsigned short hi = f2b(v);
        float r = v - b2f(hi);
        Whi[(size_t)n * YDIM + k] = hi;
        Wlo[(size_t)n * YDIM + k] = f2b(r);
    }
}

// ---------------- bf16 MFMA GEMM: C[M,N] = A[M,K] * Bt[N,K]^T ----------------
// 128x128 tile, BK=32, 4 waves, double-buffered LDS, 2-phase pipeline:
// issue next-tile global_load_lds BEFORE current-tile ds_read+MFMA; one barrier/K-step.
template<bool SPLITB, bool CBF16>
__global__ __launch_bounds__(256) void gemm_mfma(const unsigned short* __restrict__ A,
                                                 const unsigned short* __restrict__ Bh_g,
                                                 const unsigned short* __restrict__ Bl_g,
                                                 void* __restrict__ Cout,
                                                 int Kd, int Nvalid, int Cstride) {
    __shared__ unsigned short As[2][4096];
    __shared__ unsigned short Bh[2][4096];
    __shared__ unsigned short Bl[SPLITB ? 2 : 1][SPLITB ? 4096 : 4];
    int tid = threadIdx.x;
    int lane = tid & 63;
    int wave = tid >> 6;
    int wr = wave >> 1, wc = wave & 1;

    // XCD-aware bijective swizzle (nwg divisible by 8 for both launches)
    int nwg = gridDim.x * gridDim.y;
    int bid = blockIdx.y * gridDim.x + blockIdx.x;
    int cpx = nwg >> 3;
    int swz = (bid & 7) * cpx + (bid >> 3);
    int bx = swz % gridDim.x, by = swz / gridDim.x;
    int m0 = by * 128;
    int n0 = bx * 128;

    f32x4 acc[4][4];
#pragma unroll
    for (int i = 0; i < 4; ++i)
#pragma unroll
        for (int j = 0; j < 4; ++j) acc[i][j] = (f32x4){0.f, 0.f, 0.f, 0.f};

    int f0 = tid, f1 = 256 + tid;
    int row0 = f0 >> 2, ks0 = (f0 & 3) ^ ((row0 >> 1) & 3);
    int row1 = f1 >> 2, ks1 = (f1 & 3) ^ ((row1 >> 1) & 3);
    const unsigned short* ga0 = &A[(size_t)(m0 + row0) * Kd + ks0 * 8];
    const unsigned short* ga1 = &A[(size_t)(m0 + row1) * Kd + ks1 * 8];
    const unsigned short* gb0 = &Bh_g[(size_t)(n0 + row0) * Kd + ks0 * 8];
    const unsigned short* gb1 = &Bh_g[(size_t)(n0 + row1) * Kd + ks1 * 8];
    const unsigned short* gl0 = SPLITB ? &Bl_g[(size_t)(n0 + row0) * Kd + ks0 * 8] : nullptr;
    const unsigned short* gl1 = SPLITB ? &Bl_g[(size_t)(n0 + row1) * Kd + ks1 * 8] : nullptr;
    int l0 = (wave * 64) * 8;
    int l1 = (256 + wave * 64) * 8;

    int g = lane >> 4, rr = lane & 15;

#define STAGE(buf, koff) do {                                          \
        gload16(ga0 + (koff), &As[buf][l0]);                           \
        gload16(ga1 + (koff), &As[buf][l1]);                           \
        gload16(gb0 + (koff), &Bh[buf][l0]);                           \
        gload16(gb1 + (koff), &Bh[buf][l1]);                           \
        if (SPLITB) {                                                  \
            gload16(gl0 + (koff), &Bl[SPLITB ? (buf) : 0][l0]);        \
            gload16(gl1 + (koff), &Bl[SPLITB ? (buf) : 0][l1]);        \
        }                                                              \
    } while (0)

    STAGE(0, 0);
    __syncthreads();           // drain prologue stage

    int nIter = Kd >> 5;
    int cur = 0;
    for (int it = 0; it < nIter; ++it) {
        if (it + 1 < nIter) STAGE(cur ^ 1, (it + 1) * 32);   // prefetch next tile

        bf16x8 av[4], bhv[4], blv[4];
#pragma unroll
        for (int i = 0; i < 4; ++i) {
            int ra = wr * 64 + i * 16 + rr;
            av[i] = *(const bf16x8*)&As[cur][ra * 32 + ((g ^ ((ra >> 1) & 3)) * 8)];
            int rb = wc * 64 + i * 16 + rr;
            int ob = rb * 32 + ((g ^ ((rb >> 1) & 3)) * 8);
            bhv[i] = *(const bf16x8*)&Bh[cur][ob];
            if (SPLITB) blv[i] = *(const bf16x8*)&Bl[SPLITB ? cur : 0][ob];
        }
#pragma unroll
        for (int i = 0; i < 4; ++i)
#pragma unroll
            for (int j = 0; j < 4; ++j) {
                acc[i][j] = __builtin_amdgcn_mfma_f32_16x16x32_bf16(av[i], bhv[j], acc[i][j], 0, 0, 0);
                if (SPLITB)
                    acc[i][j] = __builtin_amdgcn_mfma_f32_16x16x32_bf16(av[i], blv[j], acc[i][j], 0, 0, 0);
            }

        __syncthreads();       // drains vmcnt(0): next-tile stage landed; safe to swap
        cur ^= 1;
    }
#undef STAGE

    int cg = lane >> 4, cr = lane & 15;
#pragma unroll
    for (int i = 0; i < 4; ++i)
#pragma unroll
        for (int j = 0; j < 4; ++j) {
            int colb = n0 + wc * 64 + j * 16 + cr;
            if (colb < Nvalid) {
#pragma unroll
                for (int r = 0; r < 4; ++r) {
                    int rowb = m0 + wr * 64 + i * 16 + cg * 4 + r;
                    if (CBF16)
                        ((unsigned short*)Cout)[(size_t)rowb * Cstride + colb] = f2b(acc[i][j][r]);
                    else
                        ((float*)Cout)[(size_t)rowb * Cstride + colb] = acc[i][j][r];
                }
            }
        }
}

// ---------------- fused A: conv+trig chunk partial sums (barrier-free main loop) ----------------
__global__ __launch_bounds__(256) void fused_partial(const unsigned short* __restrict__ zq,
                                                     const float* __restrict__ conv_k,
                                                     const float* __restrict__ theta,
                                                     const float* __restrict__ decay,
                                                     const float* __restrict__ anchor,
                                                     const float* __restrict__ sscale,
                                                     float* __restrict__ partials) {
    int chunk = blockIdx.x, b = blockIdx.y, t = threadIdx.x;
    int l0 = chunk * CH;
    __shared__ unsigned short zin[CH + 3][CTOT];

    for (int idx = t; idx < (CH + 3) * 36; idx += 256) {
        int r = idx / 36, c8 = (idx % 36) * 8;
        int l = l0 - 3 + r;
        u16x8 v = (u16x8)(0);
        if (l >= 0) v = *(const u16x8*)&zq[(size_t)(b * LL + l) * ZSTR + c8];
        *(u16x8*)&zin[r][c8] = v;
    }
    __syncthreads();

    int k = t >> 3;
    float cz0 = conv_k[t], cz1 = conv_k[CTOT + t], cz2 = conv_k[2 * CTOT + t], cz3 = conv_k[3 * CTOT + t];
    int sc = MEM + k;
    float cs0 = conv_k[sc], cs1 = conv_k[CTOT + sc], cs2 = conv_k[2 * CTOT + sc], cs3 = conv_k[3 * CTOT + sc];
    float xx = (k < KK - 4) ? decay[k] : anchor[k - (KK - 4)];
    float sp = (xx > 20.f) ? xx : log1pf(__expf(xx));
    float ss = sscale[k];
    float th[8];
#pragma unroll
    for (int m = 0; m < 8; ++m) th[m] = theta[t * 8 + m];
    float rs[8], is[8];
#pragma unroll
    for (int m = 0; m < 8; ++m) { rs[m] = 0.f; is[m] = 0.f; }
    float dsum = 0.f;

#pragma unroll 1
    for (int i = 0; i < CH; ++i) {
        float kv = b2f(zin[i][t]) * cz0 + b2f(zin[i + 1][t]) * cz1 +
                   b2f(zin[i + 2][t]) * cz2 + b2f(zin[i + 3][t]) * cz3;
        float s = b2f(zin[i][sc]) * cs0 + b2f(zin[i + 1][sc]) * cs1 +
                  b2f(zin[i + 2][sc]) * cs2 + b2f(zin[i + 3][sc]) * cs3;
        int l = l0 + i;
        float lw = (k < KK - 4) ? -sp * (float)(LL - 1 - l) : -sp * (float)l;
        float lp = fminf(fmaxf(ss * s, -20.f), 20.f);
        float p = __expf(lp + lw);
        dsum += p;
#pragma unroll
        for (int m = 0; m < 8; ++m) {
            float sn, cn;
            __sincosf(kv * th[m], &sn, &cn);
            rs[m] += p * cn;
            is[m] += p * sn;
        }
    }
    size_t base = ((size_t)b * NCH + chunk) * CMERG;
    *(f32x4*)&partials[base + KK + t * 8]            = (f32x4){rs[0], rs[1], rs[2], rs[3]};
    *(f32x4*)&partials[base + KK + t * 8 + 4]        = (f32x4){rs[4], rs[5], rs[6], rs[7]};
    *(f32x4*)&partials[base + KK + FLAT + t * 8]     = (f32x4){is[0], is[1], is[2], is[3]};
    *(f32x4*)&partials[base + KK + FLAT + t * 8 + 4] = (f32x4){is[4], is[5], is[6], is[7]};
    if ((t & 7) == 0) partials[base + k] = dsum;
}

// ---------------- fused B: exclusive scan of chunk partials (in place) ----------------
__global__ __launch_bounds__(256) void scan_partials(float* __restrict__ partials) {
    int t = threadIdx.x;
    int cl = t & 15, j = t >> 4;
    int c = blockIdx.x * 16 + cl;
    int b = blockIdx.y;
    float v[16];
    float s = 0.f;
#pragma unroll
    for (int i = 0; i < 16; ++i) {
        v[i] = partials[((size_t)b * NCH + j * 16 + i) * CMERG + c];
        s += v[i];
    }
    __shared__ float sums[16][17];
    sums[j][cl] = s;
    __syncthreads();
    if (j == 0) {
        float run = 0.f;
#pragma unroll
        for (int jj = 0; jj < 16; ++jj) {
            float x = sums[jj][cl];
            sums[jj][cl] = run;
            run += x;
        }
    }
    __syncthreads();
    float run = sums[j][cl];
#pragma unroll
    for (int i = 0; i < 16; ++i) {
        float x = v[i];
        partials[((size_t)b * NCH + j * 16 + i) * CMERG + c] = run;
        run += x;
    }
}

// ---------------- fused C: recompute + in-register scan + stage_d (barrier-free loop) ----------------
__global__ __launch_bounds__(256) void fused_stage(const unsigned short* __restrict__ zq,
                                                   const float* __restrict__ conv_k,
                                                   const float* __restrict__ theta,
                                                   const float* __restrict__ decay,
                                                   const float* __restrict__ anchor,
                                                   const float* __restrict__ sscale,
                                                   const float* __restrict__ partials,
                                                   const float* __restrict__ W_re,
                                                   const float* __restrict__ W_im,
                                                   const float* __restrict__ nscale,
                                                   unsigned short* __restrict__ y_act) {
    int chunk = blockIdx.x, b = blockIdx.y, t = threadIdx.x;
    int l0 = chunk * CH;
    __shared__ unsigned short zin[CH + 3][CTOT];   // raw bf16 (zq is already bf16)
    __shared__ unsigned short qall[CH][NQ];

    for (int idx = t; idx < (CH + 3) * 36; idx += 256) {
        int r = idx / 36, c8 = (idx % 36) * 8;
        int l = l0 - 3 + r;
        u16x8 v = (u16x8)(0);
        if (l >= 0) v = *(const u16x8*)&zq[(size_t)(b * LL + l) * ZSTR + c8];
        *(u16x8*)&zin[r][c8] = v;
    }
    for (int idx = t; idx < CH * (NQ / 8); idx += 256) {
        int i = idx >> 6, c8 = (idx & 63) * 8;
        *(u16x8*)&qall[i][c8] = *(const u16x8*)&zq[(size_t)(b * LL + l0 + i) * ZSTR + CTOT + c8];
    }
    __syncthreads();

    int k = t >> 3, h = t & 7, w = t >> 6;
    float cz0 = conv_k[t], cz1 = conv_k[CTOT + t], cz2 = conv_k[2 * CTOT + t], cz3 = conv_k[3 * CTOT + t];
    int sc = MEM + k;
    float cs0 = conv_k[sc], cs1 = conv_k[CTOT + sc], cs2 = conv_k[2 * CTOT + sc], cs3 = conv_k[3 * CTOT + sc];
    float xx = (k < KK - 4) ? decay[k] : anchor[k - (KK - 4)];
    float sp = (xx > 20.f) ? xx : log1pf(__expf(xx));
    float ss = sscale[k];
    float th[8];
#pragma unroll
    for (int m = 0; m < 8; ++m) th[m] = theta[t * 8 + m];
    float ns = nscale[t];
    int qb = w * 128 + h * 16;

    float wre[8][6], wim[8][6];
#pragma unroll
    for (int hh = 0; hh < 8; ++hh)
#pragma unroll
        for (int jj = 0; jj < 6; ++jj) {
            wre[hh][jj] = W_re[(k * 8 + hh) * 48 + h + 8 * jj];
            wim[hh][jj] = W_im[(k * 8 + hh) * 48 + h + 8 * jj];
        }

    size_t pbase = ((size_t)b * NCH + chunk) * CMERG;
    f32x4 r0 = *(const f32x4*)&partials[pbase + KK + t * 8];
    f32x4 r1 = *(const f32x4*)&partials[pbase + KK + t * 8 + 4];
    f32x4 i0 = *(const f32x4*)&partials[pbase + KK + FLAT + t * 8];
    f32x4 i1 = *(const f32x4*)&partials[pbase + KK + FLAT + t * 8 + 4];
    float rs[8] = {r0[0], r0[1], r0[2], r0[3], r1[0], r1[1], r1[2], r1[3]};
    float is[8] = {i0[0], i0[1], i0[2], i0[3], i1[0], i1[1], i1[2], i1[3]};
    float den = partials[pbase + k];   // exclusive denominator offset

#pragma unroll 1
    for (int i = 0; i < CH; ++i) {
        float kv = b2f(zin[i][t]) * cz0 + b2f(zin[i + 1][t]) * cz1 +
                   b2f(zin[i + 2][t]) * cz2 + b2f(zin[i + 3][t]) * cz3;
        float s = b2f(zin[i][sc]) * cs0 + b2f(zin[i + 1][sc]) * cs1 +
                  b2f(zin[i + 2][sc]) * cs2 + b2f(zin[i + 3][sc]) * cs3;
        int l = l0 + i;
        float lw = (k < KK - 4) ? -sp * (float)(LL - 1 - l) : -sp * (float)l;
        float lp = fminf(fmaxf(ss * s, -20.f), 20.f);
        float p = __expf(lp + lw);
        den += p;
        float inv = __builtin_amdgcn_rcpf(fmaxf(den, 1e-4f));
#pragma unroll
        for (int m = 0; m < 8; ++m) {
            float sn, cn;
            __sincosf(kv * th[m], &sn, &cn);
            rs[m] += p * cn;
            is[m] += p * sn;
        }
        u16x8 qv0 = *(const u16x8*)&qall[i][qb];
        u16x8 qv1 = *(const u16x8*)&qall[i][qb + 8];
        float o_re = 0.f, o_im = 0.f;
#pragma unroll
        for (int m = 0; m < 8; ++m) {
            float sre = rs[m] * inv;
            float sim = is[m] * inv;
            float qre = b2f((unsigned short)((m < 4) ? qv0[2 * m] : qv1[2 * m - 8]));
            float qim = b2f((unsigned short)((m < 4) ? qv0[2 * m + 1] : qv1[2 * m - 7]));
            o_re += sre * qre + sim * qim;
            o_im += sim * qre - sre * qim;
        }
        o_re *= ns;
        o_im *= ns;

        float y0 = 0.f, y1 = 0.f, y2 = 0.f, y3 = 0.f, y4 = 0.f, y5 = 0.f;
#define EAPPLY(HH) { float br_ = bcast8<HH>(o_re); float bi_ = bcast8<HH>(o_im); \
        y0 += br_ * wre[HH][0] + bi_ * wim[HH][0]; \
        y1 += br_ * wre[HH][1] + bi_ * wim[HH][1]; \
        y2 += br_ * wre[HH][2] + bi_ * wim[HH][2]; \
        y3 += br_ * wre[HH][3] + bi_ * wim[HH][3]; \
        y4 += br_ * wre[HH][4] + bi_ * wim[HH][4]; \
        y5 += br_ * wre[HH][5] + bi_ * wim[HH][5]; }
        EAPPLY(0) EAPPLY(1) EAPPLY(2) EAPPLY(3)
        EAPPLY(4) EAPPLY(5) EAPPLY(6) EAPPLY(7)
#undef EAPPLY

        size_t ybase = (size_t)(b * LL + l) * YDIM + k * 24 + h;
        y_act[ybase]      = f2b(fast_sigmoid_mul(y0 * y3, y3));
        y_act[ybase + 8]  = f2b(fast_sigmoid_mul(y1 * y4, y4));
        y_act[ybase + 16] = f2b(fast_sigmoid_mul(y2 * y5, y5));
    }
}

extern "C" void kernel_launch(void* const* d_in, const int* in_sizes, int n_in,
                              void* d_out, int out_size, void* d_ws, size_t ws_size,
                              hipStream_t stream) {
    const float* x      = (const float*)d_in[0];
    const float* W_mem  = (const float*)d_in[1];
    const float* conv_k = (const float*)d_in[2];
    const float* W_q    = (const float*)d_in[3];
    const float* theta  = (const float*)d_in[4];
    const float* decay  = (const float*)d_in[5];
    const float* anchor = (const float*)d_in[6];
    const float* sscale = (const float*)d_in[7];
    const float* W_re   = (const float*)d_in[8];
    const float* W_im   = (const float*)d_in[9];
    const float* nscale = (const float*)d_in[10];
    const float* W_out  = (const float*)d_in[11];
    float* out = (float*)d_out;
    float* ws = (float*)d_ws;

    // ---- d_out stash (dead before final GEMM writes d_out) ----
    unsigned short* xb = (unsigned short*)out;                 // 16,777,216 bf16 -> 8,388,608 float slots
    unsigned short* Wb = (unsigned short*)(out + 8388608);     // 896*2048 bf16 -> 917,504 slots
    unsigned short* zq = (unsigned short*)(out + 9306112);     // 8192*800 bf16 -> 3,276,800 slots, ends 12,582,912
    // ---- ws (offsets in float slots) ----
    float* partials      = ws;                                 // 2*256*4128 = 2,113,536 floats
    unsigned short* yb   = (unsigned short*)(ws + 2113536);    // 8192*768 bf16 = 3,145,728 float slots
    unsigned short* Wohi = (unsigned short*)(ws + 5259264);    // 2048*768 bf16 = 786,432 float slots
    unsigned short* Wolo = (unsigned short*)(ws + 6045696);    // ends 6,832,128 floats (27.3 MB)

    cvt_x<<<8192, 256, 0, stream>>>(x, xb);
    prep_wb<<<NPAD, 256, 0, stream>>>(W_mem, W_q, Wb);
    prep_wo<<<DD, 256, 0, stream>>>(W_out, Wohi, Wolo);

    // 1) zq = x @ [W_mem | W_q]   (8192 x 800 x 2048), bf16 out
    gemm_mfma<false, true><<<dim3(NPAD / 128, BL / 128), 256, 0, stream>>>(
        xb, Wb, (const unsigned short*)nullptr, zq, DD, ZSTR, ZSTR);
    // 2) chunk partial sums (conv+trig recompute, registers only)
    fused_partial<<<dim3(NCH, BB), 256, 0, stream>>>(zq, conv_k, theta, decay, anchor, sscale, partials);
    // 3) exclusive scan of chunk partials
    scan_partials<<<dim3(CMERG / 16, BB), 256, 0, stream>>>(partials);
    // 4) recompute + in-register inclusive scan + fused stage_d -> y (bf16)
    fused_stage<<<dim3(NCH, BB), 256, 0, stream>>>(zq, conv_k, theta, decay, anchor, sscale,
                                                   partials, W_re, W_im, nscale, yb);
    // 5) out = y @ (Wo_hi + Wo_lo)^T   (8192 x 2048 x 768), split-B for precision
    gemm_mfma<true, false><<<dim3(DD / 128, BL / 128), 256, 0, stream>>>(
        yb, Wohi, Wolo, out, YDIM, DD, DD);
}

// Round 7
// 181.500 us; speedup vs baseline: 8.8650x; 1.0274x over previous
//
#include <hip/hip_runtime.h>
#include <hip/hip_bf16.h>
#include <math.h>

// Problem constants
#define BB 2
#define LL 4096
#define DD 2048
#define KK 32
#define MEM 256          // K*H
#define CTOT 288         // MEM+K
#define NQ 512           // KQ*H*M*2
#define ZSTR 800         // CTOT + NQ (combined z|q GEMM output stride)
#define NPAD 896         // padded N for combined GEMM (7*128)
#define FLAT 2048        // K*H*M
#define CMERG 4128       // K + 2*FLAT
#define CH 16            // scan chunk length
#define NCH 256          // L / CH
#define YDIM 768         // K*24
#define KV2 1536         // virtual K for final GEMM (hi|lo concat)
#define BL (BB*LL)       // 8192

typedef __attribute__((ext_vector_type(4))) float f32x4;
typedef __attribute__((ext_vector_type(8))) short bf16x8;
typedef __attribute__((ext_vector_type(8))) unsigned short u16x8;

__device__ inline unsigned short f2b(float v) {
    __hip_bfloat16 h = __float2bfloat16(v);
    return *reinterpret_cast<unsigned short*>(&h);
}
__device__ inline float b2f(unsigned short u) {
    __hip_bfloat16 h;
    *reinterpret_cast<unsigned short*>(&h) = u;
    return __bfloat162float(h);
}

__device__ inline void gload16(const void* g, void* l) {
    __builtin_amdgcn_global_load_lds(
        (const __attribute__((address_space(1))) unsigned int*)g,
        (__attribute__((address_space(3))) unsigned int*)l, 16, 0, 0);
}

// broadcast lane (group_base | HH) within aligned 8-lane groups (BitMode swizzle)
template<int HH>
__device__ inline float bcast8(float v) {
    return __int_as_float(__builtin_amdgcn_ds_swizzle(__float_as_int(v), (HH << 5) | 0x18));
}

__device__ inline float fast_sigmoid_mul(float val, float g) {
    return val * __builtin_amdgcn_rcpf(1.f + __expf(-g));
}

// ---------------- converts / transposes ----------------
__global__ __launch_bounds__(256) void cvt_x(const float* __restrict__ x,
                                             unsigned short* __restrict__ xb) {
    size_t i = ((size_t)blockIdx.x * 256 + threadIdx.x) * 8;
    float4 a = *(const float4*)&x[i];
    float4 b = *(const float4*)&x[i + 4];
    u16x8 o;
    o[0] = f2b(a.x); o[1] = f2b(a.y); o[2] = f2b(a.z); o[3] = f2b(a.w);
    o[4] = f2b(b.x); o[5] = f2b(b.y); o[6] = f2b(b.z); o[7] = f2b(b.w);
    *(u16x8*)&xb[i] = o;
}

__global__ __launch_bounds__(256) void prep_wb(const float* __restrict__ W_mem,
                                               const float* __restrict__ W_q,
                                               unsigned short* __restrict__ Wb) {
    int n = blockIdx.x;   // 0..895
    for (int k = threadIdx.x; k < DD; k += 256) {
        float v = 0.f;
        if (n < CTOT) v = W_mem[(size_t)k * CTOT + n];
        else if (n < ZSTR) v = W_q[(size_t)k * NQ + (n - CTOT)];
        Wb[(size_t)n * DD + k] = f2b(v);
    }
}

// combined [N][1536] = [hi(768) | lo(768)] per row
__global__ __launch_bounds__(256) void prep_wo(const float* __restrict__ W_out,
                                               unsigned short* __restrict__ Wo) {
    int n = blockIdx.x;   // 0..2047
    for (int k = threadIdx.x; k < YDIM; k += 256) {
        float v = W_out[(size_t)k * DD + n];
        unsigned short hi = f2b(v);
        float r = v - b2f(hi);
        Wo[(size_t)n * KV2 + k] = hi;
        Wo[(size_t)n * KV2 + YDIM + k] = f2b(r);
    }
}

// ---------------- 128x128 bf16 MFMA GEMM (zq projection) ----------------
template<bool CBF16>
__global__ __launch_bounds__(256) void gemm_mfma(const unsigned short* __restrict__ A,
                                                 const unsigned short* __restrict__ Bh_g,
                                                 void* __restrict__ Cout,
                                                 int Kd, int Nvalid, int Cstride) {
    __shared__ unsigned short As[2][4096];
    __shared__ unsigned short Bh[2][4096];
    int tid = threadIdx.x;
    int lane = tid & 63;
    int wave = tid >> 6;
    int wr = wave >> 1, wc = wave & 1;

    int nwg = gridDim.x * gridDim.y;
    int bid = blockIdx.y * gridDim.x + blockIdx.x;
    int cpx = nwg >> 3;
    int swz = (bid & 7) * cpx + (bid >> 3);
    int bx = swz % gridDim.x, by = swz / gridDim.x;
    int m0 = by * 128;
    int n0 = bx * 128;

    f32x4 acc[4][4];
#pragma unroll
    for (int i = 0; i < 4; ++i)
#pragma unroll
        for (int j = 0; j < 4; ++j) acc[i][j] = (f32x4){0.f, 0.f, 0.f, 0.f};

    int f0 = tid, f1 = 256 + tid;
    int row0 = f0 >> 2, ks0 = (f0 & 3) ^ ((row0 >> 1) & 3);
    int row1 = f1 >> 2, ks1 = (f1 & 3) ^ ((row1 >> 1) & 3);
    const unsigned short* ga0 = &A[(size_t)(m0 + row0) * Kd + ks0 * 8];
    const unsigned short* ga1 = &A[(size_t)(m0 + row1) * Kd + ks1 * 8];
    const unsigned short* gb0 = &Bh_g[(size_t)(n0 + row0) * Kd + ks0 * 8];
    const unsigned short* gb1 = &Bh_g[(size_t)(n0 + row1) * Kd + ks1 * 8];
    int l0 = (wave * 64) * 8;
    int l1 = (256 + wave * 64) * 8;

    int g = lane >> 4, rr = lane & 15;

#define STAGE(buf, koff) do {                                          \
        gload16(ga0 + (koff), &As[buf][l0]);                           \
        gload16(ga1 + (koff), &As[buf][l1]);                           \
        gload16(gb0 + (koff), &Bh[buf][l0]);                           \
        gload16(gb1 + (koff), &Bh[buf][l1]);                           \
    } while (0)

    STAGE(0, 0);
    __syncthreads();

    int nIter = Kd >> 5;
    int cur = 0;
    for (int it = 0; it < nIter; ++it) {
        if (it + 1 < nIter) STAGE(cur ^ 1, (it + 1) * 32);

        bf16x8 av[4], bhv[4];
#pragma unroll
        for (int i = 0; i < 4; ++i) {
            int ra = wr * 64 + i * 16 + rr;
            av[i] = *(const bf16x8*)&As[cur][ra * 32 + ((g ^ ((ra >> 1) & 3)) * 8)];
            int rb = wc * 64 + i * 16 + rr;
            bhv[i] = *(const bf16x8*)&Bh[cur][rb * 32 + ((g ^ ((rb >> 1) & 3)) * 8)];
        }
#pragma unroll
        for (int i = 0; i < 4; ++i)
#pragma unroll
            for (int j = 0; j < 4; ++j)
                acc[i][j] = __builtin_amdgcn_mfma_f32_16x16x32_bf16(av[i], bhv[j], acc[i][j], 0, 0, 0);

        __syncthreads();
        cur ^= 1;
    }
#undef STAGE

    int cg = lane >> 4, cr = lane & 15;
#pragma unroll
    for (int i = 0; i < 4; ++i)
#pragma unroll
        for (int j = 0; j < 4; ++j) {
            int colb = n0 + wc * 64 + j * 16 + cr;
            if (colb < Nvalid) {
#pragma unroll
                for (int r = 0; r < 4; ++r) {
                    int rowb = m0 + wr * 64 + i * 16 + cg * 4 + r;
                    if (CBF16)
                        ((unsigned short*)Cout)[(size_t)rowb * Cstride + colb] = f2b(acc[i][j][r]);
                    else
                        ((float*)Cout)[(size_t)rowb * Cstride + colb] = acc[i][j][r];
                }
            }
        }
}

// ---------------- 256x256 8-wave phase-interleaved GEMM (final projection) ----------------
// C[M,N] = A'[M,Kv] * B[N,Kv]^T where A' virtually wraps: A'[m][k] = A[m][k % KA].
// BK=64, 4 phases/K-tile, dbuf LDS (128KB), 8-slot XOR swizzle, XCD block swizzle.
__global__ __launch_bounds__(512, 2) void gemm256(const unsigned short* __restrict__ A,
                                                  const unsigned short* __restrict__ Bm,
                                                  float* __restrict__ C,
                                                  int KA, int Kv, int Cstride) {
    __shared__ __attribute__((aligned(16))) unsigned short As[2][16384];
    __shared__ __attribute__((aligned(16))) unsigned short Bs[2][16384];
    int tid = threadIdx.x;
    int lane = tid & 63, wave = tid >> 6;
    int wm = wave >> 2, wn = wave & 3;

    int nwg = gridDim.x * gridDim.y;            // 256
    int bid = blockIdx.y * gridDim.x + blockIdx.x;
    int cpx = nwg >> 3;
    int swz = (bid & 7) * cpx + (bid >> 3);
    int bx = swz % gridDim.x, by = swz / gridDim.x;
    int m0 = by * 256, n0 = bx * 256;

    f32x4 acc[8][4];
#pragma unroll
    for (int i = 0; i < 8; ++i)
#pragma unroll
        for (int j = 0; j < 4; ++j) acc[i][j] = (f32x4){0.f, 0.f, 0.f, 0.f};

    // staging: issue j covers flat 16B-slots [j*512, j*512+512); f = j*512+tid
    // LDS slot (row=f>>3, s=f&7) holds global data col-slot s ^ (row&7)
    const unsigned short* pA[4];
    const unsigned short* pB[4];
    int ldsoff[4];
#pragma unroll
    for (int j = 0; j < 4; ++j) {
        int f = j * 512 + tid;
        int row = f >> 3, s = f & 7;
        int sg = s ^ (row & 7);
        pA[j] = A + (size_t)(m0 + row) * KA + sg * 8;
        pB[j] = Bm + (size_t)(n0 + row) * Kv + sg * 8;
        ldsoff[j] = (j * 512 + wave * 64) * 8;
    }

    int rr = lane & 15, kg = lane >> 4;

    // prologue: stage K-tile 0 fully
#pragma unroll
    for (int j = 0; j < 4; ++j) gload16(pA[j], &As[0][ldsoff[j]]);
#pragma unroll
    for (int j = 0; j < 4; ++j) gload16(pB[j], &Bs[0][ldsoff[j]]);
    __syncthreads();

    int nT = Kv >> 6;       // 24
    int cur = 0;

#define LDA(fr, t) ({ int ra_ = wm * 128 + (fr) * 16 + rr;                       \
        int sd_ = (t) * 4 + kg;                                                  \
        *(const bf16x8*)&As[cur][(ra_ * 8 + (sd_ ^ (ra_ & 7))) * 8]; })
#define LDB(fc, t) ({ int rb_ = wn * 64 + (fc) * 16 + rr;                        \
        int sd_ = (t) * 4 + kg;                                                  \
        *(const bf16x8*)&Bs[cur][(rb_ * 8 + (sd_ ^ (rb_ & 7))) * 8]; })

    for (int it = 0; it < nT; ++it) {
        int nxt = cur ^ 1;
        bool hn = (it + 1 < nT);
        int k0n = (it + 1) << 6;
        int kkA = (k0n >= KA) ? (k0n - KA) : k0n;   // A wraps (virtual [y|y])
        bf16x8 av[4], bv[4];

        // ---- phase 0: frag rows 0-3, kstep 0 ----
#pragma unroll
        for (int j = 0; j < 4; ++j) bv[j] = LDB(j, 0);
#pragma unroll
        for (int j = 0; j < 4; ++j) av[j] = LDA(j, 0);
        if (hn) { gload16(pA[0] + kkA, &As[nxt][ldsoff[0]]); gload16(pA[1] + kkA, &As[nxt][ldsoff[1]]); }
        __builtin_amdgcn_s_barrier();
        __builtin_amdgcn_s_setprio(1);
#pragma unroll
        for (int i = 0; i < 4; ++i)
#pragma unroll
            for (int j = 0; j < 4; ++j)
                acc[i][j] = __builtin_amdgcn_mfma_f32_16x16x32_bf16(av[i], bv[j], acc[i][j], 0, 0, 0);
        __builtin_amdgcn_s_setprio(0);
        __builtin_amdgcn_s_barrier();

        // ---- phase 1: frag rows 0-3, kstep 1 ----
#pragma unroll
        for (int j = 0; j < 4; ++j) bv[j] = LDB(j, 1);
#pragma unroll
        for (int j = 0; j < 4; ++j) av[j] = LDA(j, 1);
        if (hn) { gload16(pA[2] + kkA, &As[nxt][ldsoff[2]]); gload16(pA[3] + kkA, &As[nxt][ldsoff[3]]); }
        __builtin_amdgcn_s_barrier();
        __builtin_amdgcn_s_setprio(1);
#pragma unroll
        for (int i = 0; i < 4; ++i)
#pragma unroll
            for (int j = 0; j < 4; ++j)
                acc[i][j] = __builtin_amdgcn_mfma_f32_16x16x32_bf16(av[i], bv[j], acc[i][j], 0, 0, 0);
        __builtin_amdgcn_s_setprio(0);
        __builtin_amdgcn_s_barrier();

        // ---- phase 2: frag rows 4-7, kstep 0 ----
#pragma unroll
        for (int j = 0; j < 4; ++j) bv[j] = LDB(j, 0);
#pragma unroll
        for (int j = 0; j < 4; ++j) av[j] = LDA(4 + j, 0);
        if (hn) { gload16(pB[0] + k0n, &Bs[nxt][ldsoff[0]]); gload16(pB[1] + k0n, &Bs[nxt][ldsoff[1]]); }
        __builtin_amdgcn_s_barrier();
        __builtin_amdgcn_s_setprio(1);
#pragma unroll
        for (int i = 0; i < 4; ++i)
#pragma unroll
            for (int j = 0; j < 4; ++j)
                acc[4 + i][j] = __builtin_amdgcn_mfma_f32_16x16x32_bf16(av[i], bv[j], acc[4 + i][j], 0, 0, 0);
        __builtin_amdgcn_s_setprio(0);
        __builtin_amdgcn_s_barrier();

        // ---- phase 3: frag rows 4-7, kstep 1 ----
#pragma unroll
        for (int j = 0; j < 4; ++j) bv[j] = LDB(j, 1);
#pragma unroll
        for (int j = 0; j < 4; ++j) av[j] = LDA(4 + j, 1);
        if (hn) { gload16(pB[2] + k0n, &Bs[nxt][ldsoff[2]]); gload16(pB[3] + k0n, &Bs[nxt][ldsoff[3]]); }
        __builtin_amdgcn_s_barrier();
        __builtin_amdgcn_s_setprio(1);
#pragma unroll
        for (int i = 0; i < 4; ++i)
#pragma unroll
            for (int j = 0; j < 4; ++j)
                acc[4 + i][j] = __builtin_amdgcn_mfma_f32_16x16x32_bf16(av[i], bv[j], acc[4 + i][j], 0, 0, 0);
        __builtin_amdgcn_s_setprio(0);

        __syncthreads();   // drains vmcnt: next tile staged; safe to swap buffers
        cur = nxt;
    }
#undef LDA
#undef LDB

    // epilogue
#pragma unroll
    for (int i = 0; i < 8; ++i)
#pragma unroll
        for (int j = 0; j < 4; ++j) {
            int colb = n0 + wn * 64 + j * 16 + rr;
#pragma unroll
            for (int r = 0; r < 4; ++r) {
                int rowb = m0 + wm * 128 + i * 16 + kg * 4 + r;
                C[(size_t)rowb * Cstride + colb] = acc[i][j][r];
            }
        }
}

// ---------------- fused A: conv+trig chunk partial sums ----------------
__global__ __launch_bounds__(256) void fused_partial(const unsigned short* __restrict__ zq,
                                                     const float* __restrict__ conv_k,
                                                     const float* __restrict__ theta,
                                                     const float* __restrict__ decay,
                                                     const float* __restrict__ anchor,
                                                     const float* __restrict__ sscale,
                                                     float* __restrict__ partials) {
    int chunk = blockIdx.x, b = blockIdx.y, t = threadIdx.x;
    int l0 = chunk * CH;
    __shared__ unsigned short zin[CH + 3][CTOT];

    for (int idx = t; idx < (CH + 3) * 36; idx += 256) {
        int r = idx / 36, c8 = (idx % 36) * 8;
        int l = l0 - 3 + r;
        u16x8 v = (u16x8)(0);
        if (l >= 0) v = *(const u16x8*)&zq[(size_t)(b * LL + l) * ZSTR + c8];
        *(u16x8*)&zin[r][c8] = v;
    }
    __syncthreads();

    int k = t >> 3;
    float cz0 = conv_k[t], cz1 = conv_k[CTOT + t], cz2 = conv_k[2 * CTOT + t], cz3 = conv_k[3 * CTOT + t];
    int sc = MEM + k;
    float cs0 = conv_k[sc], cs1 = conv_k[CTOT + sc], cs2 = conv_k[2 * CTOT + sc], cs3 = conv_k[3 * CTOT + sc];
    float xx = (k < KK - 4) ? decay[k] : anchor[k - (KK - 4)];
    float sp = (xx > 20.f) ? xx : log1pf(__expf(xx));
    float ss = sscale[k];
    float th[8];
#pragma unroll
    for (int m = 0; m < 8; ++m) th[m] = theta[t * 8 + m];
    float rs[8], is[8];
#pragma unroll
    for (int m = 0; m < 8; ++m) { rs[m] = 0.f; is[m] = 0.f; }
    float dsum = 0.f;

#pragma unroll 1
    for (int i = 0; i < CH; ++i) {
        float kv = b2f(zin[i][t]) * cz0 + b2f(zin[i + 1][t]) * cz1 +
                   b2f(zin[i + 2][t]) * cz2 + b2f(zin[i + 3][t]) * cz3;
        float s = b2f(zin[i][sc]) * cs0 + b2f(zin[i + 1][sc]) * cs1 +
                  b2f(zin[i + 2][sc]) * cs2 + b2f(zin[i + 3][sc]) * cs3;
        int l = l0 + i;
        float lw = (k < KK - 4) ? -sp * (float)(LL - 1 - l) : -sp * (float)l;
        float lp = fminf(fmaxf(ss * s, -20.f), 20.f);
        float p = __expf(lp + lw);
        dsum += p;
#pragma unroll
        for (int m = 0; m < 8; ++m) {
            float sn, cn;
            __sincosf(kv * th[m], &sn, &cn);
            rs[m] += p * cn;
            is[m] += p * sn;
        }
    }
    size_t base = ((size_t)b * NCH + chunk) * CMERG;
    *(f32x4*)&partials[base + KK + t * 8]            = (f32x4){rs[0], rs[1], rs[2], rs[3]};
    *(f32x4*)&partials[base + KK + t * 8 + 4]        = (f32x4){rs[4], rs[5], rs[6], rs[7]};
    *(f32x4*)&partials[base + KK + FLAT + t * 8]     = (f32x4){is[0], is[1], is[2], is[3]};
    *(f32x4*)&partials[base + KK + FLAT + t * 8 + 4] = (f32x4){is[4], is[5], is[6], is[7]};
    if ((t & 7) == 0) partials[base + k] = dsum;
}

// ---------------- fused B: exclusive scan of chunk partials (in place) ----------------
__global__ __launch_bounds__(256) void scan_partials(float* __restrict__ partials) {
    int t = threadIdx.x;
    int cl = t & 15, j = t >> 4;
    int c = blockIdx.x * 16 + cl;
    int b = blockIdx.y;
    float v[16];
    float s = 0.f;
#pragma unroll
    for (int i = 0; i < 16; ++i) {
        v[i] = partials[((size_t)b * NCH + j * 16 + i) * CMERG + c];
        s += v[i];
    }
    __shared__ float sums[16][17];
    sums[j][cl] = s;
    __syncthreads();
    if (j == 0) {
        float run = 0.f;
#pragma unroll
        for (int jj = 0; jj < 16; ++jj) {
            float x = sums[jj][cl];
            sums[jj][cl] = run;
            run += x;
        }
    }
    __syncthreads();
    float run = sums[j][cl];
#pragma unroll
    for (int i = 0; i < 16; ++i) {
        float x = v[i];
        partials[((size_t)b * NCH + j * 16 + i) * CMERG + c] = run;
        run += x;
    }
}

// ---------------- fused C: recompute + in-register scan + stage_d ----------------
__global__ __launch_bounds__(256) void fused_stage(const unsigned short* __restrict__ zq,
                                                   const float* __restrict__ conv_k,
                                                   const float* __restrict__ theta,
                                                   const float* __restrict__ decay,
                                                   const float* __restrict__ anchor,
                                                   const float* __restrict__ sscale,
                                                   const float* __restrict__ partials,
                                                   const float* __restrict__ W_re,
                                                   const float* __restrict__ W_im,
                                                   const float* __restrict__ nscale,
                                                   unsigned short* __restrict__ y_act) {
    int chunk = blockIdx.x, b = blockIdx.y, t = threadIdx.x;
    int l0 = chunk * CH;
    __shared__ unsigned short zin[CH + 3][CTOT];
    __shared__ unsigned short qall[CH][NQ];

    for (int idx = t; idx < (CH + 3) * 36; idx += 256) {
        int r = idx / 36, c8 = (idx % 36) * 8;
        int l = l0 - 3 + r;
        u16x8 v = (u16x8)(0);
        if (l >= 0) v = *(const u16x8*)&zq[(size_t)(b * LL + l) * ZSTR + c8];
        *(u16x8*)&zin[r][c8] = v;
    }
    for (int idx = t; idx < CH * (NQ / 8); idx += 256) {
        int i = idx >> 6, c8 = (idx & 63) * 8;
        *(u16x8*)&qall[i][c8] = *(const u16x8*)&zq[(size_t)(b * LL + l0 + i) * ZSTR + CTOT + c8];
    }
    __syncthreads();

    int k = t >> 3, h = t & 7, w = t >> 6;
    float cz0 = conv_k[t], cz1 = conv_k[CTOT + t], cz2 = conv_k[2 * CTOT + t], cz3 = conv_k[3 * CTOT + t];
    int sc = MEM + k;
    float cs0 = conv_k[sc], cs1 = conv_k[CTOT + sc], cs2 = conv_k[2 * CTOT + sc], cs3 = conv_k[3 * CTOT + sc];
    float xx = (k < KK - 4) ? decay[k] : anchor[k - (KK - 4)];
    float sp = (xx > 20.f) ? xx : log1pf(__expf(xx));
    float ss = sscale[k];
    float th[8];
#pragma unroll
    for (int m = 0; m < 8; ++m) th[m] = theta[t * 8 + m];
    float ns = nscale[t];
    int qb = w * 128 + h * 16;

    float wre[8][6], wim[8][6];
#pragma unroll
    for (int hh = 0; hh < 8; ++hh)
#pragma unroll
        for (int jj = 0; jj < 6; ++jj) {
            wre[hh][jj] = W_re[(k * 8 + hh) * 48 + h + 8 * jj];
            wim[hh][jj] = W_im[(k * 8 + hh) * 48 + h + 8 * jj];
        }

    size_t pbase = ((size_t)b * NCH + chunk) * CMERG;
    f32x4 r0 = *(const f32x4*)&partials[pbase + KK + t * 8];
    f32x4 r1 = *(const f32x4*)&partials[pbase + KK + t * 8 + 4];
    f32x4 i0 = *(const f32x4*)&partials[pbase + KK + FLAT + t * 8];
    f32x4 i1 = *(const f32x4*)&partials[pbase + KK + FLAT + t * 8 + 4];
    float rs[8] = {r0[0], r0[1], r0[2], r0[3], r1[0], r1[1], r1[2], r1[3]};
    float is[8] = {i0[0], i0[1], i0[2], i0[3], i1[0], i1[1], i1[2], i1[3]};
    float den = partials[pbase + k];

#pragma unroll 1
    for (int i = 0; i < CH; ++i) {
        float kv = b2f(zin[i][t]) * cz0 + b2f(zin[i + 1][t]) * cz1 +
                   b2f(zin[i + 2][t]) * cz2 + b2f(zin[i + 3][t]) * cz3;
        float s = b2f(zin[i][sc]) * cs0 + b2f(zin[i + 1][sc]) * cs1 +
                  b2f(zin[i + 2][sc]) * cs2 + b2f(zin[i + 3][sc]) * cs3;
        int l = l0 + i;
        float lw = (k < KK - 4) ? -sp * (float)(LL - 1 - l) : -sp * (float)l;
        float lp = fminf(fmaxf(ss * s, -20.f), 20.f);
        float p = __expf(lp + lw);
        den += p;
        float inv = __builtin_amdgcn_rcpf(fmaxf(den, 1e-4f));
#pragma unroll
        for (int m = 0; m < 8; ++m) {
            float sn, cn;
            __sincosf(kv * th[m], &sn, &cn);
            rs[m] += p * cn;
            is[m] += p * sn;
        }
        u16x8 qv0 = *(const u16x8*)&qall[i][qb];
        u16x8 qv1 = *(const u16x8*)&qall[i][qb + 8];
        float o_re = 0.f, o_im = 0.f;
#pragma unroll
        for (int m = 0; m < 8; ++m) {
            float sre = rs[m] * inv;
            float sim = is[m] * inv;
            float qre = b2f((unsigned short)((m < 4) ? qv0[2 * m] : qv1[2 * m - 8]));
            float qim = b2f((unsigned short)((m < 4) ? qv0[2 * m + 1] : qv1[2 * m - 7]));
            o_re += sre * qre + sim * qim;
            o_im += sim * qre - sre * qim;
        }
        o_re *= ns;
        o_im *= ns;

        float y0 = 0.f, y1 = 0.f, y2 = 0.f, y3 = 0.f, y4 = 0.f, y5 = 0.f;
#define EAPPLY(HH) { float br_ = bcast8<HH>(o_re); float bi_ = bcast8<HH>(o_im); \
        y0 += br_ * wre[HH][0] + bi_ * wim[HH][0]; \
        y1 += br_ * wre[HH][1] + bi_ * wim[HH][1]; \
        y2 += br_ * wre[HH][2] + bi_ * wim[HH][2]; \
        y3 += br_ * wre[HH][3] + bi_ * wim[HH][3]; \
        y4 += br_ * wre[HH][4] + bi_ * wim[HH][4]; \
        y5 += br_ * wre[HH][5] + bi_ * wim[HH][5]; }
        EAPPLY(0) EAPPLY(1) EAPPLY(2) EAPPLY(3)
        EAPPLY(4) EAPPLY(5) EAPPLY(6) EAPPLY(7)
#undef EAPPLY

        size_t ybase = (size_t)(b * LL + l) * YDIM + k * 24 + h;
        y_act[ybase]      = f2b(fast_sigmoid_mul(y0 * y3, y3));
        y_act[ybase + 8]  = f2b(fast_sigmoid_mul(y1 * y4, y4));
        y_act[ybase + 16] = f2b(fast_sigmoid_mul(y2 * y5, y5));
    }
}

extern "C" void kernel_launch(void* const* d_in, const int* in_sizes, int n_in,
                              void* d_out, int out_size, void* d_ws, size_t ws_size,
                              hipStream_t stream) {
    const float* x      = (const float*)d_in[0];
    const float* W_mem  = (const float*)d_in[1];
    const float* conv_k = (const float*)d_in[2];
    const float* W_q    = (const float*)d_in[3];
    const float* theta  = (const float*)d_in[4];
    const float* decay  = (const float*)d_in[5];
    const float* anchor = (const float*)d_in[6];
    const float* sscale = (const float*)d_in[7];
    const float* W_re   = (const float*)d_in[8];
    const float* W_im   = (const float*)d_in[9];
    const float* nscale = (const float*)d_in[10];
    const float* W_out  = (const float*)d_in[11];
    float* out = (float*)d_out;
    float* ws = (float*)d_ws;

    // ---- d_out stash (dead before final GEMM writes d_out) ----
    unsigned short* xb = (unsigned short*)out;                 // 16,777,216 bf16 -> 8,388,608 float slots
    unsigned short* Wb = (unsigned short*)(out + 8388608);     // 896*2048 bf16 -> 917,504 slots
    unsigned short* zq = (unsigned short*)(out + 9306112);     // 8192*800 bf16 -> 3,276,800 slots, ends 12,582,912
    // ---- ws (offsets in float slots) ----
    float* partials      = ws;                                 // 2*256*4128 = 2,113,536 floats
    unsigned short* yb   = (unsigned short*)(ws + 2113536);    // 8192*768 bf16 = 3,145,728 float slots
    unsigned short* Wo   = (unsigned short*)(ws + 5259264);    // 2048*1536 bf16 = 1,572,864 float slots
                                                               // ends 6,832,128 floats (27.3 MB)

    cvt_x<<<8192, 256, 0, stream>>>(x, xb);
    prep_wb<<<NPAD, 256, 0, stream>>>(W_mem, W_q, Wb);
    prep_wo<<<DD, 256, 0, stream>>>(W_out, Wo);

    // 1) zq = x @ [W_mem | W_q]   (8192 x 800 x 2048), bf16 out
    gemm_mfma<true><<<dim3(NPAD / 128, BL / 128), 256, 0, stream>>>(
        xb, Wb, zq, DD, ZSTR, ZSTR);
    // 2) chunk partial sums (conv+trig recompute, registers only)
    fused_partial<<<dim3(NCH, BB), 256, 0, stream>>>(zq, conv_k, theta, decay, anchor, sscale, partials);
    // 3) exclusive scan of chunk partials
    scan_partials<<<dim3(CMERG / 16, BB), 256, 0, stream>>>(partials);
    // 4) recompute + in-register inclusive scan + fused stage_d -> y (bf16)
    fused_stage<<<dim3(NCH, BB), 256, 0, stream>>>(zq, conv_k, theta, decay, anchor, sscale,
                                                   partials, W_re, W_im, nscale, yb);
    // 5) out = [y|y] @ Wo^T  (8192 x 2048 x virtual-1536): split-B folded into K
    gemm256<<<dim3(DD / 256, BL / 256), 512, 0, stream>>>(yb, Wo, out, YDIM, KV2, DD);
}

// Round 8
// 180.395 us; speedup vs baseline: 8.9193x; 1.0061x over previous
//
#include <hip/hip_runtime.h>
#include <hip/hip_bf16.h>
#include <math.h>

// Problem constants
#define BB 2
#define LL 4096
#define DD 2048
#define KK 32
#define MEM 256          // K*H
#define CTOT 288         // MEM+K
#define NQ 512           // KQ*H*M*2
#define ZSTR 800         // CTOT + NQ (combined z|q GEMM output stride)
#define NPAD 896         // padded N for combined GEMM (7*128)
#define FLAT 2048        // K*H*M
#define CMERG 4128       // K + 2*FLAT
#define CH 16            // scan chunk length
#define NCH 256          // L / CH
#define YDIM 768         // K*24
#define KV2 1536         // virtual K for final GEMM (hi|lo concat)
#define BL (BB*LL)       // 8192

typedef __attribute__((ext_vector_type(4))) float f32x4;
typedef __attribute__((ext_vector_type(8))) short bf16x8;
typedef __attribute__((ext_vector_type(8))) unsigned short u16x8;

__device__ inline unsigned short f2b(float v) {
    __hip_bfloat16 h = __float2bfloat16(v);
    return *reinterpret_cast<unsigned short*>(&h);
}
__device__ inline float b2f(unsigned short u) {
    __hip_bfloat16 h;
    *reinterpret_cast<unsigned short*>(&h) = u;
    return __bfloat162float(h);
}

__device__ inline void gload16(const void* g, void* l) {
    __builtin_amdgcn_global_load_lds(
        (const __attribute__((address_space(1))) unsigned int*)g,
        (__attribute__((address_space(3))) unsigned int*)l, 16, 0, 0);
}

// broadcast lane (group_base | HH) within aligned 8-lane groups (BitMode swizzle)
template<int HH>
__device__ inline float bcast8(float v) {
    return __int_as_float(__builtin_amdgcn_ds_swizzle(__float_as_int(v), (HH << 5) | 0x18));
}

__device__ inline float fast_sigmoid_mul(float val, float g) {
    return val * __builtin_amdgcn_rcpf(1.f + __expf(-g));
}

// ---------------- converts / transposes ----------------
__global__ __launch_bounds__(256) void cvt_x(const float* __restrict__ x,
                                             unsigned short* __restrict__ xb) {
    size_t i = ((size_t)blockIdx.x * 256 + threadIdx.x) * 8;
    float4 a = *(const float4*)&x[i];
    float4 b = *(const float4*)&x[i + 4];
    u16x8 o;
    o[0] = f2b(a.x); o[1] = f2b(a.y); o[2] = f2b(a.z); o[3] = f2b(a.w);
    o[4] = f2b(b.x); o[5] = f2b(b.y); o[6] = f2b(b.z); o[7] = f2b(b.w);
    *(u16x8*)&xb[i] = o;
}

__global__ __launch_bounds__(256) void prep_wb(const float* __restrict__ W_mem,
                                               const float* __restrict__ W_q,
                                               unsigned short* __restrict__ Wb) {
    int n = blockIdx.x;   // 0..895
    for (int k = threadIdx.x; k < DD; k += 256) {
        float v = 0.f;
        if (n < CTOT) v = W_mem[(size_t)k * CTOT + n];
        else if (n < ZSTR) v = W_q[(size_t)k * NQ + (n - CTOT)];
        Wb[(size_t)n * DD + k] = f2b(v);
    }
}

// combined [N][1536] = [hi(768) | lo(768)] per row
__global__ __launch_bounds__(256) void prep_wo(const float* __restrict__ W_out,
                                               unsigned short* __restrict__ Wo) {
    int n = blockIdx.x;   // 0..2047
    for (int k = threadIdx.x; k < YDIM; k += 256) {
        float v = W_out[(size_t)k * DD + n];
        unsigned short hi = f2b(v);
        float r = v - b2f(hi);
        Wo[(size_t)n * KV2 + k] = hi;
        Wo[(size_t)n * KV2 + YDIM + k] = f2b(r);
    }
}

// ---------------- 128x128 bf16 MFMA GEMM (zq projection) ----------------
template<bool CBF16>
__global__ __launch_bounds__(256) void gemm_mfma(const unsigned short* __restrict__ A,
                                                 const unsigned short* __restrict__ Bh_g,
                                                 void* __restrict__ Cout,
                                                 int Kd, int Nvalid, int Cstride) {
    __shared__ unsigned short As[2][4096];
    __shared__ unsigned short Bh[2][4096];
    int tid = threadIdx.x;
    int lane = tid & 63;
    int wave = tid >> 6;
    int wr = wave >> 1, wc = wave & 1;

    int nwg = gridDim.x * gridDim.y;
    int bid = blockIdx.y * gridDim.x + blockIdx.x;
    int cpx = nwg >> 3;
    int swz = (bid & 7) * cpx + (bid >> 3);
    int bx = swz % gridDim.x, by = swz / gridDim.x;
    int m0 = by * 128;
    int n0 = bx * 128;

    f32x4 acc[4][4];
#pragma unroll
    for (int i = 0; i < 4; ++i)
#pragma unroll
        for (int j = 0; j < 4; ++j) acc[i][j] = (f32x4){0.f, 0.f, 0.f, 0.f};

    int f0 = tid, f1 = 256 + tid;
    int row0 = f0 >> 2, ks0 = (f0 & 3) ^ ((row0 >> 1) & 3);
    int row1 = f1 >> 2, ks1 = (f1 & 3) ^ ((row1 >> 1) & 3);
    const unsigned short* ga0 = &A[(size_t)(m0 + row0) * Kd + ks0 * 8];
    const unsigned short* ga1 = &A[(size_t)(m0 + row1) * Kd + ks1 * 8];
    const unsigned short* gb0 = &Bh_g[(size_t)(n0 + row0) * Kd + ks0 * 8];
    const unsigned short* gb1 = &Bh_g[(size_t)(n0 + row1) * Kd + ks1 * 8];
    int l0 = (wave * 64) * 8;
    int l1 = (256 + wave * 64) * 8;

    int g = lane >> 4, rr = lane & 15;

#define STAGE(buf, koff) do {                                          \
        gload16(ga0 + (koff), &As[buf][l0]);                           \
        gload16(ga1 + (koff), &As[buf][l1]);                           \
        gload16(gb0 + (koff), &Bh[buf][l0]);                           \
        gload16(gb1 + (koff), &Bh[buf][l1]);                           \
    } while (0)

    STAGE(0, 0);
    __syncthreads();

    int nIter = Kd >> 5;
    int cur = 0;
    for (int it = 0; it < nIter; ++it) {
        if (it + 1 < nIter) STAGE(cur ^ 1, (it + 1) * 32);

        bf16x8 av[4], bhv[4];
#pragma unroll
        for (int i = 0; i < 4; ++i) {
            int ra = wr * 64 + i * 16 + rr;
            av[i] = *(const bf16x8*)&As[cur][ra * 32 + ((g ^ ((ra >> 1) & 3)) * 8)];
            int rb = wc * 64 + i * 16 + rr;
            bhv[i] = *(const bf16x8*)&Bh[cur][rb * 32 + ((g ^ ((rb >> 1) & 3)) * 8)];
        }
#pragma unroll
        for (int i = 0; i < 4; ++i)
#pragma unroll
            for (int j = 0; j < 4; ++j)
                acc[i][j] = __builtin_amdgcn_mfma_f32_16x16x32_bf16(av[i], bhv[j], acc[i][j], 0, 0, 0);

        __syncthreads();
        cur ^= 1;
    }
#undef STAGE

    int cg = lane >> 4, cr = lane & 15;
#pragma unroll
    for (int i = 0; i < 4; ++i)
#pragma unroll
        for (int j = 0; j < 4; ++j) {
            int colb = n0 + wc * 64 + j * 16 + cr;
            if (colb < Nvalid) {
#pragma unroll
                for (int r = 0; r < 4; ++r) {
                    int rowb = m0 + wr * 64 + i * 16 + cg * 4 + r;
                    if (CBF16)
                        ((unsigned short*)Cout)[(size_t)rowb * Cstride + colb] = f2b(acc[i][j][r]);
                    else
                        ((float*)Cout)[(size_t)rowb * Cstride + colb] = acc[i][j][r];
                }
            }
        }
}

// ---------------- 256x256 8-wave phase-interleaved GEMM, counted-vmcnt (T4) ----------------
// C[M,N] = A'[M,Kv] * B[N,Kv]^T with A'[m][k] = A[m][k % KA].
// BK=64, 4 phases/K-tile, dbuf LDS (128KB), 8-slot XOR swizzle, XCD block swizzle.
// Stage order for tile u+1: p0:B01 p1:B23 p2:A02 p3:A13.
// Waits: vmcnt(4)@p1 (protects A13(u) read at p2), vmcnt(2)@p3 (protects B+A02(u+1) at u+1.p0).
__global__ __launch_bounds__(512, 2) void gemm256(const unsigned short* __restrict__ A,
                                                  const unsigned short* __restrict__ Bm,
                                                  float* __restrict__ C,
                                                  int KA, int Kv, int Cstride) {
    __shared__ __attribute__((aligned(16))) unsigned short As[2][16384];
    __shared__ __attribute__((aligned(16))) unsigned short Bs[2][16384];
    int tid = threadIdx.x;
    int lane = tid & 63, wave = tid >> 6;
    int wm = wave >> 2, wn = wave & 3;

    int nwg = gridDim.x * gridDim.y;            // 256
    int bid = blockIdx.y * gridDim.x + blockIdx.x;
    int cpx = nwg >> 3;
    int swz = (bid & 7) * cpx + (bid >> 3);
    int bx = swz % gridDim.x, by = swz / gridDim.x;
    int m0 = by * 256, n0 = bx * 256;

    f32x4 acc[8][4];
#pragma unroll
    for (int i = 0; i < 8; ++i)
#pragma unroll
        for (int j = 0; j < 4; ++j) acc[i][j] = (f32x4){0.f, 0.f, 0.f, 0.f};

    // staging group j: flat 16B-slot f = j*512+tid; LDS (row=f>>3, s=f&7) holds global slot s^(row&7)
    const unsigned short* pA[4];
    const unsigned short* pB[4];
    int ldsoff[4];
#pragma unroll
    for (int j = 0; j < 4; ++j) {
        int f = j * 512 + tid;
        int row = f >> 3, s = f & 7;
        int sg = s ^ (row & 7);
        pA[j] = A + (size_t)(m0 + row) * KA + sg * 8;
        pB[j] = Bm + (size_t)(n0 + row) * Kv + sg * 8;
        ldsoff[j] = (j * 512 + wave * 64) * 8;
    }

    int rr = lane & 15, kg = lane >> 4;

    // prologue: stage K-tile 0 in deadline order, counted wait, raw barrier
    gload16(pB[0], &Bs[0][ldsoff[0]]); gload16(pB[1], &Bs[0][ldsoff[1]]);
    gload16(pB[2], &Bs[0][ldsoff[2]]); gload16(pB[3], &Bs[0][ldsoff[3]]);
    gload16(pA[0], &As[0][ldsoff[0]]); gload16(pA[2], &As[0][ldsoff[2]]);
    gload16(pA[1], &As[0][ldsoff[1]]); gload16(pA[3], &As[0][ldsoff[3]]);
    asm volatile("s_waitcnt vmcnt(2)" ::: "memory");   // B all + A0,A2 landed (A1,A3 may fly)
    __builtin_amdgcn_s_barrier();

    int nT = Kv >> 6;       // 24
    int cur = 0;

#define LDA(fr, t) ({ int ra_ = wm * 128 + (fr) * 16 + rr;                       \
        int sd_ = (t) * 4 + kg;                                                  \
        *(const bf16x8*)&As[cur][(ra_ * 8 + (sd_ ^ (ra_ & 7))) * 8]; })
#define LDB(fc, t) ({ int rb_ = wn * 64 + (fc) * 16 + rr;                        \
        int sd_ = (t) * 4 + kg;                                                  \
        *(const bf16x8*)&Bs[cur][(rb_ * 8 + (sd_ ^ (rb_ & 7))) * 8]; })

#define MFMA16(io) do {                                                           \
    __builtin_amdgcn_s_setprio(1);                                                \
    _Pragma("unroll")                                                             \
    for (int i = 0; i < 4; ++i)                                                   \
        _Pragma("unroll")                                                         \
        for (int j = 0; j < 4; ++j)                                               \
            acc[(io) + i][j] = __builtin_amdgcn_mfma_f32_16x16x32_bf16(av[i], bv[j], acc[(io) + i][j], 0, 0, 0); \
    __builtin_amdgcn_s_setprio(0);                                                \
} while (0)

    for (int it = 0; it < nT; ++it) {
        int nxt = cur ^ 1;
        bool hn = (it + 1 < nT);
        int k0n = (it + 1) << 6;
        int kkA = (k0n >= KA) ? (k0n - KA) : k0n;   // A wraps (virtual [y|y])
        bf16x8 av[4], bv[4];

        // ---- phase 0: frag rows 0-3, kstep 0 | stage B01(next) ----
#pragma unroll
        for (int j = 0; j < 4; ++j) bv[j] = LDB(j, 0);
#pragma unroll
        for (int j = 0; j < 4; ++j) av[j] = LDA(j, 0);
        if (hn) { gload16(pB[0] + k0n, &Bs[nxt][ldsoff[0]]); gload16(pB[1] + k0n, &Bs[nxt][ldsoff[1]]); }
        __builtin_amdgcn_s_barrier();
        MFMA16(0);
        __builtin_amdgcn_s_barrier();

        // ---- phase 1: frag rows 0-3, kstep 1 | stage B23(next) | vmcnt protects A13(cur) ----
#pragma unroll
        for (int j = 0; j < 4; ++j) bv[j] = LDB(j, 1);
#pragma unroll
        for (int j = 0; j < 4; ++j) av[j] = LDA(j, 1);
        if (hn) {
            gload16(pB[2] + k0n, &Bs[nxt][ldsoff[2]]); gload16(pB[3] + k0n, &Bs[nxt][ldsoff[3]]);
            asm volatile("s_waitcnt vmcnt(4)" ::: "memory");
        } else {
            asm volatile("s_waitcnt vmcnt(0)" ::: "memory");
        }
        __builtin_amdgcn_s_barrier();
        MFMA16(0);
        __builtin_amdgcn_s_barrier();

        // ---- phase 2: frag rows 4-7, kstep 0 | stage A02(next) ----
#pragma unroll
        for (int j = 0; j < 4; ++j) bv[j] = LDB(j, 0);
#pragma unroll
        for (int j = 0; j < 4; ++j) av[j] = LDA(4 + j, 0);
        if (hn) { gload16(pA[0] + kkA, &As[nxt][ldsoff[0]]); gload16(pA[2] + kkA, &As[nxt][ldsoff[2]]); }
        __builtin_amdgcn_s_barrier();
        MFMA16(4);
        __builtin_amdgcn_s_barrier();

        // ---- phase 3: frag rows 4-7, kstep 1 | stage A13(next) | vmcnt protects B+A02(next) ----
#pragma unroll
        for (int j = 0; j < 4; ++j) bv[j] = LDB(j, 1);
#pragma unroll
        for (int j = 0; j < 4; ++j) av[j] = LDA(4 + j, 1);
        if (hn) {
            gload16(pA[1] + kkA, &As[nxt][ldsoff[1]]); gload16(pA[3] + kkA, &As[nxt][ldsoff[3]]);
            asm volatile("s_waitcnt vmcnt(2)" ::: "memory");
        }
        __builtin_amdgcn_s_barrier();
        MFMA16(4);
        __builtin_amdgcn_s_barrier();

        cur = nxt;
    }
#undef LDA
#undef LDB
#undef MFMA16

    // epilogue
#pragma unroll
    for (int i = 0; i < 8; ++i)
#pragma unroll
        for (int j = 0; j < 4; ++j) {
            int colb = n0 + wn * 64 + j * 16 + rr;
#pragma unroll
            for (int r = 0; r < 4; ++r) {
                int rowb = m0 + wm * 128 + i * 16 + kg * 4 + r;
                C[(size_t)rowb * Cstride + colb] = acc[i][j][r];
            }
        }
}

// ---------------- fused A: conv+trig chunk partial sums ----------------
__global__ __launch_bounds__(256) void fused_partial(const unsigned short* __restrict__ zq,
                                                     const float* __restrict__ conv_k,
                                                     const float* __restrict__ theta,
                                                     const float* __restrict__ decay,
                                                     const float* __restrict__ anchor,
                                                     const float* __restrict__ sscale,
                                                     float* __restrict__ partials) {
    int chunk = blockIdx.x, b = blockIdx.y, t = threadIdx.x;
    int l0 = chunk * CH;
    __shared__ unsigned short zin[CH + 3][CTOT];

    for (int idx = t; idx < (CH + 3) * 36; idx += 256) {
        int r = idx / 36, c8 = (idx % 36) * 8;
        int l = l0 - 3 + r;
        u16x8 v = (u16x8)(0);
        if (l >= 0) v = *(const u16x8*)&zq[(size_t)(b * LL + l) * ZSTR + c8];
        *(u16x8*)&zin[r][c8] = v;
    }
    __syncthreads();

    int k = t >> 3;
    float cz0 = conv_k[t], cz1 = conv_k[CTOT + t], cz2 = conv_k[2 * CTOT + t], cz3 = conv_k[3 * CTOT + t];
    int sc = MEM + k;
    float cs0 = conv_k[sc], cs1 = conv_k[CTOT + sc], cs2 = conv_k[2 * CTOT + sc], cs3 = conv_k[3 * CTOT + sc];
    float xx = (k < KK - 4) ? decay[k] : anchor[k - (KK - 4)];
    float sp = (xx > 20.f) ? xx : log1pf(__expf(xx));
    float ss = sscale[k];
    float th[8];
#pragma unroll
    for (int m = 0; m < 8; ++m) th[m] = theta[t * 8 + m];
    float rs[8], is[8];
#pragma unroll
    for (int m = 0; m < 8; ++m) { rs[m] = 0.f; is[m] = 0.f; }
    float dsum = 0.f;

#pragma unroll 1
    for (int i = 0; i < CH; ++i) {
        float kv = b2f(zin[i][t]) * cz0 + b2f(zin[i + 1][t]) * cz1 +
                   b2f(zin[i + 2][t]) * cz2 + b2f(zin[i + 3][t]) * cz3;
        float s = b2f(zin[i][sc]) * cs0 + b2f(zin[i + 1][sc]) * cs1 +
                  b2f(zin[i + 2][sc]) * cs2 + b2f(zin[i + 3][sc]) * cs3;
        int l = l0 + i;
        float lw = (k < KK - 4) ? -sp * (float)(LL - 1 - l) : -sp * (float)l;
        float lp = fminf(fmaxf(ss * s, -20.f), 20.f);
        float p = __expf(lp + lw);
        dsum += p;
#pragma unroll
        for (int m = 0; m < 8; ++m) {
            float sn, cn;
            __sincosf(kv * th[m], &sn, &cn);
            rs[m] += p * cn;
            is[m] += p * sn;
        }
    }
    size_t base = ((size_t)b * NCH + chunk) * CMERG;
    *(f32x4*)&partials[base + KK + t * 8]            = (f32x4){rs[0], rs[1], rs[2], rs[3]};
    *(f32x4*)&partials[base + KK + t * 8 + 4]        = (f32x4){rs[4], rs[5], rs[6], rs[7]};
    *(f32x4*)&partials[base + KK + FLAT + t * 8]     = (f32x4){is[0], is[1], is[2], is[3]};
    *(f32x4*)&partials[base + KK + FLAT + t * 8 + 4] = (f32x4){is[4], is[5], is[6], is[7]};
    if ((t & 7) == 0) partials[base + k] = dsum;
}

// ---------------- fused B: exclusive scan of chunk partials (in place) ----------------
__global__ __launch_bounds__(256) void scan_partials(float* __restrict__ partials) {
    int t = threadIdx.x;
    int cl = t & 15, j = t >> 4;
    int c = blockIdx.x * 16 + cl;
    int b = blockIdx.y;
    float v[16];
    float s = 0.f;
#pragma unroll
    for (int i = 0; i < 16; ++i) {
        v[i] = partials[((size_t)b * NCH + j * 16 + i) * CMERG + c];
        s += v[i];
    }
    __shared__ float sums[16][17];
    sums[j][cl] = s;
    __syncthreads();
    if (j == 0) {
        float run = 0.f;
#pragma unroll
        for (int jj = 0; jj < 16; ++jj) {
            float x = sums[jj][cl];
            sums[jj][cl] = run;
            run += x;
        }
    }
    __syncthreads();
    float run = sums[j][cl];
#pragma unroll
    for (int i = 0; i < 16; ++i) {
        float x = v[i];
        partials[((size_t)b * NCH + j * 16 + i) * CMERG + c] = run;
        run += x;
    }
}

// ---------------- fused C: recompute + in-register scan + stage_d ----------------
__global__ __launch_bounds__(256) void fused_stage(const unsigned short* __restrict__ zq,
                                                   const float* __restrict__ conv_k,
                                                   const float* __restrict__ theta,
                                                   const float* __restrict__ decay,
                                                   const float* __restrict__ anchor,
                                                   const float* __restrict__ sscale,
                                                   const float* __restrict__ partials,
                                                   const float* __restrict__ W_re,
                                                   const float* __restrict__ W_im,
                                                   const float* __restrict__ nscale,
                                                   unsigned short* __restrict__ y_act) {
    int chunk = blockIdx.x, b = blockIdx.y, t = threadIdx.x;
    int l0 = chunk * CH;
    __shared__ unsigned short zin[CH + 3][CTOT];
    __shared__ unsigned short qall[CH][NQ];

    for (int idx = t; idx < (CH + 3) * 36; idx += 256) {
        int r = idx / 36, c8 = (idx % 36) * 8;
        int l = l0 - 3 + r;
        u16x8 v = (u16x8)(0);
        if (l >= 0) v = *(const u16x8*)&zq[(size_t)(b * LL + l) * ZSTR + c8];
        *(u16x8*)&zin[r][c8] = v;
    }
    for (int idx = t; idx < CH * (NQ / 8); idx += 256) {
        int i = idx >> 6, c8 = (idx & 63) * 8;
        *(u16x8*)&qall[i][c8] = *(const u16x8*)&zq[(size_t)(b * LL + l0 + i) * ZSTR + CTOT + c8];
    }
    __syncthreads();

    int k = t >> 3, h = t & 7, w = t >> 6;
    float cz0 = conv_k[t], cz1 = conv_k[CTOT + t], cz2 = conv_k[2 * CTOT + t], cz3 = conv_k[3 * CTOT + t];
    int sc = MEM + k;
    float cs0 = conv_k[sc], cs1 = conv_k[CTOT + sc], cs2 = conv_k[2 * CTOT + sc], cs3 = conv_k[3 * CTOT + sc];
    float xx = (k < KK - 4) ? decay[k] : anchor[k - (KK - 4)];
    float sp = (xx > 20.f) ? xx : log1pf(__expf(xx));
    float ss = sscale[k];
    float th[8];
#pragma unroll
    for (int m = 0; m < 8; ++m) th[m] = theta[t * 8 + m];
    float ns = nscale[t];
    int qb = w * 128 + h * 16;

    float wre[8][6], wim[8][6];
#pragma unroll
    for (int hh = 0; hh < 8; ++hh)
#pragma unroll
        for (int jj = 0; jj < 6; ++jj) {
            wre[hh][jj] = W_re[(k * 8 + hh) * 48 + h + 8 * jj];
            wim[hh][jj] = W_im[(k * 8 + hh) * 48 + h + 8 * jj];
        }

    size_t pbase = ((size_t)b * NCH + chunk) * CMERG;
    f32x4 r0 = *(const f32x4*)&partials[pbase + KK + t * 8];
    f32x4 r1 = *(const f32x4*)&partials[pbase + KK + t * 8 + 4];
    f32x4 i0 = *(const f32x4*)&partials[pbase + KK + FLAT + t * 8];
    f32x4 i1 = *(const f32x4*)&partials[pbase + KK + FLAT + t * 8 + 4];
    float rs[8] = {r0[0], r0[1], r0[2], r0[3], r1[0], r1[1], r1[2], r1[3]};
    float is[8] = {i0[0], i0[1], i0[2], i0[3], i1[0], i1[1], i1[2], i1[3]};
    float den = partials[pbase + k];

#pragma unroll 1
    for (int i = 0; i < CH; ++i) {
        float kv = b2f(zin[i][t]) * cz0 + b2f(zin[i + 1][t]) * cz1 +
                   b2f(zin[i + 2][t]) * cz2 + b2f(zin[i + 3][t]) * cz3;
        float s = b2f(zin[i][sc]) * cs0 + b2f(zin[i + 1][sc]) * cs1 +
                  b2f(zin[i + 2][sc]) * cs2 + b2f(zin[i + 3][sc]) * cs3;
        int l = l0 + i;
        float lw = (k < KK - 4) ? -sp * (float)(LL - 1 - l) : -sp * (float)l;
        float lp = fminf(fmaxf(ss * s, -20.f), 20.f);
        float p = __expf(lp + lw);
        den += p;
        float inv = __builtin_amdgcn_rcpf(fmaxf(den, 1e-4f));
#pragma unroll
        for (int m = 0; m < 8; ++m) {
            float sn, cn;
            __sincosf(kv * th[m], &sn, &cn);
            rs[m] += p * cn;
            is[m] += p * sn;
        }
        u16x8 qv0 = *(const u16x8*)&qall[i][qb];
        u16x8 qv1 = *(const u16x8*)&qall[i][qb + 8];
        float o_re = 0.f, o_im = 0.f;
#pragma unroll
        for (int m = 0; m < 8; ++m) {
            float sre = rs[m] * inv;
            float sim = is[m] * inv;
            float qre = b2f((unsigned short)((m < 4) ? qv0[2 * m] : qv1[2 * m - 8]));
            float qim = b2f((unsigned short)((m < 4) ? qv0[2 * m + 1] : qv1[2 * m - 7]));
            o_re += sre * qre + sim * qim;
            o_im += sim * qre - sre * qim;
        }
        o_re *= ns;
        o_im *= ns;

        float y0 = 0.f, y1 = 0.f, y2 = 0.f, y3 = 0.f, y4 = 0.f, y5 = 0.f;
#define EAPPLY(HH) { float br_ = bcast8<HH>(o_re); float bi_ = bcast8<HH>(o_im); \
        y0 += br_ * wre[HH][0] + bi_ * wim[HH][0]; \
        y1 += br_ * wre[HH][1] + bi_ * wim[HH][1]; \
        y2 += br_ * wre[HH][2] + bi_ * wim[HH][2]; \
        y3 += br_ * wre[HH][3] + bi_ * wim[HH][3]; \
        y4 += br_ * wre[HH][4] + bi_ * wim[HH][4]; \
        y5 += br_ * wre[HH][5] + bi_ * wim[HH][5]; }
        EAPPLY(0) EAPPLY(1) EAPPLY(2) EAPPLY(3)
        EAPPLY(4) EAPPLY(5) EAPPLY(6) EAPPLY(7)
#undef EAPPLY

        size_t ybase = (size_t)(b * LL + l) * YDIM + k * 24 + h;
        y_act[ybase]      = f2b(fast_sigmoid_mul(y0 * y3, y3));
        y_act[ybase + 8]  = f2b(fast_sigmoid_mul(y1 * y4, y4));
        y_act[ybase + 16] = f2b(fast_sigmoid_mul(y2 * y5, y5));
    }
}

extern "C" void kernel_launch(void* const* d_in, const int* in_sizes, int n_in,
                              void* d_out, int out_size, void* d_ws, size_t ws_size,
                              hipStream_t stream) {
    const float* x      = (const float*)d_in[0];
    const float* W_mem  = (const float*)d_in[1];
    const float* conv_k = (const float*)d_in[2];
    const float* W_q    = (const float*)d_in[3];
    const float* theta  = (const float*)d_in[4];
    const float* decay  = (const float*)d_in[5];
    const float* anchor = (const float*)d_in[6];
    const float* sscale = (const float*)d_in[7];
    const float* W_re   = (const float*)d_in[8];
    const float* W_im   = (const float*)d_in[9];
    const float* nscale = (const float*)d_in[10];
    const float* W_out  = (const float*)d_in[11];
    float* out = (float*)d_out;
    float* ws = (float*)d_ws;

    // ---- d_out stash (dead before final GEMM writes d_out) ----
    unsigned short* xb = (unsigned short*)out;                 // 16,777,216 bf16 -> 8,388,608 float slots
    unsigned short* Wb = (unsigned short*)(out + 8388608);     // 896*2048 bf16 -> 917,504 slots
    unsigned short* zq = (unsigned short*)(out + 9306112);     // 8192*800 bf16 -> 3,276,800 slots, ends 12,582,912
    // ---- ws (offsets in float slots) ----
    float* partials      = ws;                                 // 2*256*4128 = 2,113,536 floats
    unsigned short* yb   = (unsigned short*)(ws + 2113536);    // 8192*768 bf16 = 3,145,728 float slots
    unsigned short* Wo   = (unsigned short*)(ws + 5259264);    // 2048*1536 bf16 = 1,572,864 float slots
                                                               // ends 6,832,128 floats (27.3 MB)

    cvt_x<<<8192, 256, 0, stream>>>(x, xb);
    prep_wb<<<NPAD, 256, 0, stream>>>(W_mem, W_q, Wb);
    prep_wo<<<DD, 256, 0, stream>>>(W_out, Wo);

    // 1) zq = x @ [W_mem | W_q]   (8192 x 800 x 2048), bf16 out
    gemm_mfma<true><<<dim3(NPAD / 128, BL / 128), 256, 0, stream>>>(
        xb, Wb, zq, DD, ZSTR, ZSTR);
    // 2) chunk partial sums (conv+trig recompute, registers only)
    fused_partial<<<dim3(NCH, BB), 256, 0, stream>>>(zq, conv_k, theta, decay, anchor, sscale, partials);
    // 3) exclusive scan of chunk partials
    scan_partials<<<dim3(CMERG / 16, BB), 256, 0, stream>>>(partials);
    // 4) recompute + in-register inclusive scan + fused stage_d -> y (bf16)
    fused_stage<<<dim3(NCH, BB), 256, 0, stream>>>(zq, conv_k, theta, decay, anchor, sscale,
                                                   partials, W_re, W_im, nscale, yb);
    // 5) out = [y|y] @ Wo^T  (8192 x 2048 x virtual-1536): split-B folded into K
    gemm256<<<dim3(DD / 256, BL / 256), 512, 0, stream>>>(yb, Wo, out, YDIM, KV2, DD);
}